// Round 11
// baseline (1493.552 us; speedup 1.0000x reference)
//
#include <hip/hip_runtime.h>
#include <hip/hip_bf16.h>

// Problem constants
#define B_    256
#define K_    64
#define D_    256
#define T_    8
#define NROW  (B_*K_)

typedef short short8v __attribute__((ext_vector_type(8)));
typedef float f32x4  __attribute__((ext_vector_type(4)));

// ---------- device helpers ----------
__device__ __forceinline__ float fexp2(float x) { return __builtin_amdgcn_exp2f(x); }
__device__ __forceinline__ float flog2(float x) { return __builtin_amdgcn_logf(x); }

__device__ __forceinline__ float sigmoid_f(float x) {
  return 1.f / (1.f + fexp2(x * -1.4426950408889634f));
}
__device__ __forceinline__ float tanh_fast(float x) {
  float xc = fminf(fmaxf(x, -30.f), 30.f);
  float t = fexp2(xc * 2.8853900817779268f);   // e^(2x)
  return (t - 1.f) / (t + 1.f);
}
__device__ __forceinline__ float gelu_f(float x) {
  return 0.5f * x * (1.f + erff(x * 0.70710678118654752440f));
}
__device__ __forceinline__ unsigned short f2bf(float x) {
  __hip_bfloat16 h = __float2bfloat16(x);
  return *reinterpret_cast<unsigned short*>(&h);
}
__device__ __forceinline__ float bfss(unsigned short s) {
  return __uint_as_float(((unsigned int)s) << 16);
}
__device__ __forceinline__ float muS_f(float x, float a2, float b2) {
  float mid = 0.5f * (a2 + b2);
  float inv = 1.f / (b2 - a2 + 1e-12f);
  if (x > b2)  return 1.f;
  if (x > mid) { float u = (b2 - x) * inv; return 1.f - 2.f * u * u; }
  if (x > a2)  { float u = (x - a2) * inv; return 2.f * u * u; }
  return 0.f;
}
__device__ __forceinline__ float pow_abs(float z, float e2b) {
  return fexp2(e2b * flog2(fabsf(z)));
}
__device__ __forceinline__ float defuzz_one(float rb_, float rs_, float ab, float bb) {
  float e2b = 2.f * bb;
  float inv_ab = 1.f / ab;
  float cb = 4.f * tanh_fast(rb_);
  float num = 0.f, den = 0.f;
  #pragma unroll
  for (int j = 0; j < 41; ++j) {
    float gj = -4.f + 0.2f * (float)j;
    float mu = 1.f / (1.f + pow_abs((gj - cb) * inv_ab, e2b));
    num += gj * mu; den += mu;
  }
  float cenb = num / (den + 1e-12f);
  float cs = 4.f * tanh_fast(rs_);
  float as_ = fminf(fmaxf(cs - 1.f, -4.f), 4.f);
  float bs_ = fminf(fmaxf(cs + 1.f, -4.f), 4.f);
  num = 0.f; den = 0.f;
  {
    float mid = 0.5f * (as_ + bs_);
    float inv = 1.f / (bs_ - as_ + 1e-12f);
    #pragma unroll
    for (int j = 0; j < 41; ++j) {
      float gj = -4.f + 0.2f * (float)j;
      float mu;
      if (gj > bs_)      mu = 1.f;
      else if (gj > mid) { float u = (bs_ - gj) * inv; mu = 1.f - 2.f * u * u; }
      else if (gj > as_) { float u = (gj - as_) * inv; mu = 2.f * u * u; }
      else               mu = 0.f;
      num += gj * mu; den += mu;
    }
  }
  float cens = num / (den + 1e-12f);
  return 0.5f * cenb + 0.5f * cens;
}

// ---------- one-time: weight transposes / bf16 conversions ----------
__global__ __launch_bounds__(256) void k_convert(
    const float* __restrict__ W1, const float* __restrict__ Vf, const float* __restrict__ Vi,
    const float* __restrict__ W2, const float* __restrict__ FT,
    const float* __restrict__ WkI, const float* __restrict__ WkG,
    unsigned short* __restrict__ B1t, unsigned short* __restrict__ W2t,
    unsigned short* __restrict__ FTbf,
    float* __restrict__ WkIt, float* __restrict__ WkGt)
{
  int idx = blockIdx.x * 256 + threadIdx.x;
  if (idx < 262144) {
    int n = idx >> 8, k = idx & 255;
    float v = (n < 512) ? W1[(size_t)k*512 + n]
            : (n < 768) ? Vf[(size_t)k*256 + (n-512)]
                        : Vi[(size_t)k*256 + (n-768)];
    B1t[idx] = f2bf(v);
  } else if (idx < 393216) {
    int j = idx - 262144;
    int n = j >> 9, k = j & 511;
    W2t[j] = f2bf(W2[(size_t)k*256 + n]);
  } else if (idx < 409600) {
    int j = idx - 393216;
    FTbf[j] = f2bf(FT[j]);
  } else if (idx < 475136) {
    int j = idx - 409600;
    int k = j >> 8, n = j & 255;
    WkIt[j] = WkI[(size_t)n*256 + k];
  } else if (idx < 540672) {
    int j = idx - 475136;
    int k = j >> 8, n = j & 255;
    WkGt[j] = WkG[(size_t)n*256 + k];
  }
}

// ---------- precompute stage 1: lr/g linear + fuzzify ----------
__global__ __launch_bounds__(256) void k_pre_lin(
    const float* __restrict__ wsi, const float* __restrict__ gen,
    const float* __restrict__ W_lr, const float* __restrict__ b_lr,
    const float* __restrict__ W_g,  const float* __restrict__ b_g,
    const float* __restrict__ a_p,  const float* __restrict__ b_p,
    float* __restrict__ lrf, float* __restrict__ gf)
{
  int g_ix = blockIdx.x;
  int half = g_ix >> 4, tile = g_ix & 15;
  int bx = tile & 3, by = tile >> 2;
  int n0 = bx * 64, m0 = by * 64;
  const float* A    = half ? gen  : wsi;
  const float* Bm   = half ? W_g  : W_lr;
  const float* bias = half ? b_g  : b_lr;
  float* outp       = half ? gf   : lrf;
  int KK            = half ? 512  : 1024;
  float ab = fmaxf(a_p[0], 0.001f), bb = fmaxf(b_p[0], 0.001f);
  float e2b = 2.f * bb, inv_ab = 1.f / ab;

  __shared__ float As[16][64];
  __shared__ float Bs[16][64];
  int tid = threadIdx.x, tx = tid & 15, ty = tid >> 4;
  float acc[4][4] = {};
  int am = tid >> 2, ak = (tid & 3) * 4;
  int bk = tid >> 4, bn = (tid & 15) * 4;
  const float* arow = A + (size_t)(m0 + am) * KK;
  for (int k0 = 0; k0 < KK; k0 += 16) {
    float4 av = *(const float4*)(arow + k0 + ak);
    As[ak+0][am] = av.x; As[ak+1][am] = av.y; As[ak+2][am] = av.z; As[ak+3][am] = av.w;
    *(float4*)&Bs[bk][bn] = *(const float4*)(Bm + (size_t)(k0 + bk) * 256 + n0 + bn);
    __syncthreads();
    #pragma unroll
    for (int kk = 0; kk < 16; ++kk) {
      float a0 = As[kk][ty*4+0], a1 = As[kk][ty*4+1], a2 = As[kk][ty*4+2], a3 = As[kk][ty*4+3];
      float b0 = Bs[kk][tx*4+0], b1 = Bs[kk][tx*4+1], b2 = Bs[kk][tx*4+2], b3 = Bs[kk][tx*4+3];
      acc[0][0]=fmaf(a0,b0,acc[0][0]); acc[0][1]=fmaf(a0,b1,acc[0][1]); acc[0][2]=fmaf(a0,b2,acc[0][2]); acc[0][3]=fmaf(a0,b3,acc[0][3]);
      acc[1][0]=fmaf(a1,b0,acc[1][0]); acc[1][1]=fmaf(a1,b1,acc[1][1]); acc[1][2]=fmaf(a1,b2,acc[1][2]); acc[1][3]=fmaf(a1,b3,acc[1][3]);
      acc[2][0]=fmaf(a2,b0,acc[2][0]); acc[2][1]=fmaf(a2,b1,acc[2][1]); acc[2][2]=fmaf(a2,b2,acc[2][2]); acc[2][3]=fmaf(a2,b3,acc[2][3]);
      acc[3][0]=fmaf(a3,b0,acc[3][0]); acc[3][1]=fmaf(a3,b1,acc[3][1]); acc[3][2]=fmaf(a3,b2,acc[3][2]); acc[3][3]=fmaf(a3,b3,acc[3][3]);
    }
    __syncthreads();
  }
  #pragma unroll
  for (int i = 0; i < 4; ++i) {
    int row = m0 + ty*4 + i;
    #pragma unroll
    for (int j = 0; j < 4; ++j) {
      int col = n0 + tx*4 + j;
      float v = acc[i][j] + bias[col];
      float xs = 4.f * tanh_fast(v * 0.25f);
      outp[(size_t)row*512 + col]       = 1.f / (1.f + pow_abs(xs * inv_ab, e2b));
      outp[(size_t)row*512 + col + 256] = muS_f(xs, -1.f, 1.f);
    }
  }
}

// ---------- precompute stage 2: QI = lrf@WqI, QG = gf@WqG ----------
__global__ __launch_bounds__(256) void k_pre_q(
    const float* __restrict__ lrf, const float* __restrict__ gf,
    const float* __restrict__ WqI, const float* __restrict__ WqG,
    float* __restrict__ QI, float* __restrict__ QG)
{
  int g_ix = blockIdx.x;
  int half = g_ix >> 4, tile = g_ix & 15;
  int bx = tile & 3, by = tile >> 2;
  int n0 = bx * 64, m0 = by * 64;
  const float* A  = half ? gf  : lrf;
  const float* Bm = half ? WqG : WqI;
  float* outp     = half ? QG  : QI;

  __shared__ float As[16][64];
  __shared__ float Bs[16][64];
  int tid = threadIdx.x, tx = tid & 15, ty = tid >> 4;
  float acc[4][4] = {};
  int am = tid >> 2, ak = (tid & 3) * 4;
  int bk = tid >> 4, bn = (tid & 15) * 4;
  const float* arow = A + (size_t)(m0 + am) * 512;
  for (int k0 = 0; k0 < 512; k0 += 16) {
    float4 av = *(const float4*)(arow + k0 + ak);
    As[ak+0][am] = av.x; As[ak+1][am] = av.y; As[ak+2][am] = av.z; As[ak+3][am] = av.w;
    *(float4*)&Bs[bk][bn] = *(const float4*)(Bm + (size_t)(k0 + bk) * 256 + n0 + bn);
    __syncthreads();
    #pragma unroll
    for (int kk = 0; kk < 16; ++kk) {
      float a0 = As[kk][ty*4+0], a1 = As[kk][ty*4+1], a2 = As[kk][ty*4+2], a3 = As[kk][ty*4+3];
      float b0 = Bs[kk][tx*4+0], b1 = Bs[kk][tx*4+1], b2 = Bs[kk][tx*4+2], b3 = Bs[kk][tx*4+3];
      acc[0][0]=fmaf(a0,b0,acc[0][0]); acc[0][1]=fmaf(a0,b1,acc[0][1]); acc[0][2]=fmaf(a0,b2,acc[0][2]); acc[0][3]=fmaf(a0,b3,acc[0][3]);
      acc[1][0]=fmaf(a1,b0,acc[1][0]); acc[1][1]=fmaf(a1,b1,acc[1][1]); acc[1][2]=fmaf(a1,b2,acc[1][2]); acc[1][3]=fmaf(a1,b3,acc[1][3]);
      acc[2][0]=fmaf(a2,b0,acc[2][0]); acc[2][1]=fmaf(a2,b1,acc[2][1]); acc[2][2]=fmaf(a2,b2,acc[2][2]); acc[2][3]=fmaf(a2,b3,acc[2][3]);
      acc[3][0]=fmaf(a3,b0,acc[3][0]); acc[3][1]=fmaf(a3,b1,acc[3][1]); acc[3][2]=fmaf(a3,b2,acc[3][2]); acc[3][3]=fmaf(a3,b3,acc[3][3]);
    }
    __syncthreads();
  }
  #pragma unroll
  for (int i = 0; i < 4; ++i) {
    float4 v = make_float4(acc[i][0], acc[i][1], acc[i][2], acc[i][3]);
    *(float4*)(outp + (size_t)(m0 + ty*4 + i) * 256 + n0 + tx*4) = v;
  }
}

// ---------- precompute stage 3: qIp = QI@WkIt, qGp = QG@WkGt ----------
__global__ __launch_bounds__(256) void k_pre_qp(
    const float* __restrict__ QI, const float* __restrict__ QG,
    const float* __restrict__ WkIt, const float* __restrict__ WkGt,
    float* __restrict__ qIp, float* __restrict__ qGp)
{
  int g_ix = blockIdx.x;
  int half = g_ix >> 4, tile = g_ix & 15;
  int bx = tile & 3, by = tile >> 2;
  int n0 = bx * 64, m0 = by * 64;
  const float* A  = half ? QG   : QI;
  const float* Bm = half ? WkGt : WkIt;
  float* outp     = half ? qGp  : qIp;

  __shared__ float As[16][64];
  __shared__ float Bs[16][64];
  int tid = threadIdx.x, tx = tid & 15, ty = tid >> 4;
  float acc[4][4] = {};
  int am = tid >> 2, ak = (tid & 3) * 4;
  int bk = tid >> 4, bn = (tid & 15) * 4;
  const float* arow = A + (size_t)(m0 + am) * 256;
  for (int k0 = 0; k0 < 256; k0 += 16) {
    float4 av = *(const float4*)(arow + k0 + ak);
    As[ak+0][am] = av.x; As[ak+1][am] = av.y; As[ak+2][am] = av.z; As[ak+3][am] = av.w;
    *(float4*)&Bs[bk][bn] = *(const float4*)(Bm + (size_t)(k0 + bk) * 256 + n0 + bn);
    __syncthreads();
    #pragma unroll
    for (int kk = 0; kk < 16; ++kk) {
      float a0 = As[kk][ty*4+0], a1 = As[kk][ty*4+1], a2 = As[kk][ty*4+2], a3 = As[kk][ty*4+3];
      float b0 = Bs[kk][tx*4+0], b1 = Bs[kk][tx*4+1], b2 = Bs[kk][tx*4+2], b3 = Bs[kk][tx*4+3];
      acc[0][0]=fmaf(a0,b0,acc[0][0]); acc[0][1]=fmaf(a0,b1,acc[0][1]); acc[0][2]=fmaf(a0,b2,acc[0][2]); acc[0][3]=fmaf(a0,b3,acc[0][3]);
      acc[1][0]=fmaf(a1,b0,acc[1][0]); acc[1][1]=fmaf(a1,b1,acc[1][1]); acc[1][2]=fmaf(a1,b2,acc[1][2]); acc[1][3]=fmaf(a1,b3,acc[1][3]);
      acc[2][0]=fmaf(a2,b0,acc[2][0]); acc[2][1]=fmaf(a2,b1,acc[2][1]); acc[2][2]=fmaf(a2,b2,acc[2][2]); acc[2][3]=fmaf(a2,b3,acc[2][3]);
      acc[3][0]=fmaf(a3,b0,acc[3][0]); acc[3][1]=fmaf(a3,b1,acc[3][1]); acc[3][2]=fmaf(a3,b2,acc[3][2]); acc[3][3]=fmaf(a3,b3,acc[3][3]);
    }
    __syncthreads();
  }
  #pragma unroll
  for (int i = 0; i < 4; ++i) {
    float4 v = make_float4(acc[i][0], acc[i][1], acc[i][2], acc[i][3]);
    *(float4*)(outp + (size_t)(m0 + ty*4 + i) * 256 + n0 + tx*4) = v;
  }
}

// ---------- per step: ftbar (scores+softmax+weighted-sum), one block per batch ----------
__global__ __launch_bounds__(256) void k_ftbar(
    const unsigned short* __restrict__ Fb_all, int bcast,
    const float* __restrict__ qIp, const float* __restrict__ qGp,
    float* __restrict__ ftbI, float* __restrict__ ftbG)
{
  __shared__ __align__(16) char smem[38912];
  int b = blockIdx.x, t = threadIdx.x;
  short* Fs  = (short*)smem;                  // [64][264] bf16
  float* qv  = (float*)(smem + 33792);        // [512]
  float* red = (float*)(smem + 35840);        // [512]
  float* prl = (float*)(smem + 37888);        // p [128]

  const unsigned short* Fsrc = bcast ? Fb_all : (Fb_all + (size_t)b * K_ * D_);
  #pragma unroll
  for (int i = 0; i < 8; ++i) {
    int sidx = (i * 256 + t) * 8;
    int row = sidx >> 8, col = sidx & 255;
    *(float4*)&Fs[row * 264 + col] = *(const float4*)&Fsrc[sidx];
  }
  qv[t]       = qIp[(size_t)b*256 + t];
  qv[256 + t] = qGp[(size_t)b*256 + t];
  __syncthreads();
  {
    int k = t & 63, part = t >> 6;
    const unsigned int* frow = (const unsigned int*)&Fs[k * 264 + part * 64];
    const float* q0 = qv + part * 64;
    const float* q1 = qv + 256 + part * 64;
    float s0 = 0.f, s1 = 0.f;
    #pragma unroll
    for (int d2 = 0; d2 < 32; ++d2) {
      unsigned int pr = frow[d2];
      float f0 = __uint_as_float(pr << 16);
      float f1 = __uint_as_float(pr & 0xffff0000u);
      s0 = fmaf(f1, q0[2*d2+1], fmaf(f0, q0[2*d2], s0));
      s1 = fmaf(f1, q1[2*d2+1], fmaf(f0, q1[2*d2], s1));
    }
    red[t] = s0; red[256 + t] = s1;
  }
  __syncthreads();
  if (t < 128) {
    int which = t >> 6, kk = t & 63;
    const float* rp = red + which * 256;
    float s = (rp[kk] + rp[64+kk] + rp[128+kk] + rp[192+kk]) * (1.f/16.f);
    float m = s;
    for (int off = 32; off; off >>= 1) m = fmaxf(m, __shfl_xor(m, off, 64));
    float e = fexp2((s - m) * 1.4426950408889634f);
    float sum = e;
    for (int off = 32; off; off >>= 1) sum += __shfl_xor(sum, off, 64);
    prl[which * 64 + kk] = e / sum;
  }
  __syncthreads();
  {
    float f0 = 0.f, f1 = 0.f;
    #pragma unroll 8
    for (int kk = 0; kk < 64; ++kk) {
      float fv = bfss((unsigned short)Fs[kk * 264 + t]);
      f0 = fmaf(prl[kk],      fv, f0);
      f1 = fmaf(prl[64 + kk], fv, f1);
    }
    ftbI[(size_t)b*256 + t] = f0;
    ftbG[(size_t)b*256 + t] = f1;
  }
}

// ---------- per step: rt = [ftbI@WvI | ftbG@WvG]  M=256 N=1024 K=256 ----------
__global__ __launch_bounds__(256) void k_rt(
    const float* __restrict__ ftbI, const float* __restrict__ ftbG,
    const float* __restrict__ WvI,  const float* __restrict__ WvG,
    float* __restrict__ rt)
{
  int bx = blockIdx.x & 15, by = blockIdx.x >> 4;
  int n0 = bx * 64, m0 = by * 64;
  const float* Ap = (n0 < 512) ? ftbI : ftbG;
  const float* Bp = (n0 < 512) ? WvI  : WvG;
  int nb = (n0 < 512) ? n0 : n0 - 512;
  __shared__ float As[16][64];
  __shared__ float Bs[16][64];
  int tid = threadIdx.x, tx = tid & 15, ty = tid >> 4;
  float acc[4][4] = {};
  int am = tid >> 2, ak = (tid & 3) * 4;
  int bk = tid >> 4, bn = (tid & 15) * 4;
  const float* arow = Ap + (size_t)(m0 + am) * 256;
  for (int k0 = 0; k0 < 256; k0 += 16) {
    float4 av = *(const float4*)(arow + k0 + ak);
    As[ak+0][am] = av.x; As[ak+1][am] = av.y; As[ak+2][am] = av.z; As[ak+3][am] = av.w;
    *(float4*)&Bs[bk][bn] = *(const float4*)(Bp + (size_t)(k0 + bk) * 512 + nb + bn);
    __syncthreads();
    #pragma unroll
    for (int kk = 0; kk < 16; ++kk) {
      float a0 = As[kk][ty*4+0], a1 = As[kk][ty*4+1], a2 = As[kk][ty*4+2], a3 = As[kk][ty*4+3];
      float b0 = Bs[kk][tx*4+0], b1 = Bs[kk][tx*4+1], b2 = Bs[kk][tx*4+2], b3 = Bs[kk][tx*4+3];
      acc[0][0]=fmaf(a0,b0,acc[0][0]); acc[0][1]=fmaf(a0,b1,acc[0][1]); acc[0][2]=fmaf(a0,b2,acc[0][2]); acc[0][3]=fmaf(a0,b3,acc[0][3]);
      acc[1][0]=fmaf(a1,b0,acc[1][0]); acc[1][1]=fmaf(a1,b1,acc[1][1]); acc[1][2]=fmaf(a1,b2,acc[1][2]); acc[1][3]=fmaf(a1,b3,acc[1][3]);
      acc[2][0]=fmaf(a2,b0,acc[2][0]); acc[2][1]=fmaf(a2,b1,acc[2][1]); acc[2][2]=fmaf(a2,b2,acc[2][2]); acc[2][3]=fmaf(a2,b3,acc[2][3]);
      acc[3][0]=fmaf(a3,b0,acc[3][0]); acc[3][1]=fmaf(a3,b1,acc[3][1]); acc[3][2]=fmaf(a3,b2,acc[3][2]); acc[3][3]=fmaf(a3,b3,acc[3][3]);
    }
    __syncthreads();
  }
  #pragma unroll
  for (int i = 0; i < 4; ++i) {
    float4 v = make_float4(acc[i][0], acc[i][1], acc[i][2], acc[i][3]);
    *(float4*)(rt + (size_t)(m0 + ty*4 + i) * 1024 + n0 + tx*4) = v;
  }
}

// ---------- per step: defuzzify -> r ----------
__global__ __launch_bounds__(256) void k_defuzz(
    const float* __restrict__ rt,
    const float* __restrict__ a_p, const float* __restrict__ b_p,
    float* __restrict__ r_out)
{
  int b = blockIdx.x, t = threadIdx.x;
  float ab = fmaxf(a_p[0], 0.001f), bb = fmaxf(b_p[0], 0.001f);
  const float* rb = rt + (size_t)b * 1024;
  float rI = defuzz_one(rb[t],       rb[256 + t], ab, bb);
  float rG = defuzz_one(rb[512 + t], rb[768 + t], ab, bb);
  r_out[(size_t)b*256 + t] = 0.5f * rI + 0.5f * rG;
}

// ---------- per step: rW = r @ [W1 | Wf | Wi]  M=256 N=1024 K=256 ----------
__global__ __launch_bounds__(256) void k_rW(
    const float* __restrict__ r,
    const float* __restrict__ W1, const float* __restrict__ Wf, const float* __restrict__ Wi,
    float* __restrict__ rW1, float* __restrict__ rWf, float* __restrict__ rWi)
{
  int bx = blockIdx.x & 15, by = blockIdx.x >> 4;
  int n0 = bx * 64, m0 = by * 64;
  const float* Bp; int ldb, nb;
  if (n0 < 512)      { Bp = W1; ldb = 512; nb = n0; }
  else if (n0 < 768) { Bp = Wf; ldb = 256; nb = n0 - 512; }
  else               { Bp = Wi; ldb = 256; nb = n0 - 768; }
  __shared__ float As[16][64];
  __shared__ float Bs[16][64];
  int tid = threadIdx.x, tx = tid & 15, ty = tid >> 4;
  float acc[4][4] = {};
  int am = tid >> 2, ak = (tid & 3) * 4;
  int bk = tid >> 4, bn = (tid & 15) * 4;
  const float* arow = r + (size_t)(m0 + am) * 256;
  for (int k0 = 0; k0 < 256; k0 += 16) {
    float4 av = *(const float4*)(arow + k0 + ak);
    As[ak+0][am] = av.x; As[ak+1][am] = av.y; As[ak+2][am] = av.z; As[ak+3][am] = av.w;
    *(float4*)&Bs[bk][bn] = *(const float4*)(Bp + (size_t)(k0 + bk) * ldb + nb + bn);
    __syncthreads();
    #pragma unroll
    for (int kk = 0; kk < 16; ++kk) {
      float a0 = As[kk][ty*4+0], a1 = As[kk][ty*4+1], a2 = As[kk][ty*4+2], a3 = As[kk][ty*4+3];
      float b0 = Bs[kk][tx*4+0], b1 = Bs[kk][tx*4+1], b2 = Bs[kk][tx*4+2], b3 = Bs[kk][tx*4+3];
      acc[0][0]=fmaf(a0,b0,acc[0][0]); acc[0][1]=fmaf(a0,b1,acc[0][1]); acc[0][2]=fmaf(a0,b2,acc[0][2]); acc[0][3]=fmaf(a0,b3,acc[0][3]);
      acc[1][0]=fmaf(a1,b0,acc[1][0]); acc[1][1]=fmaf(a1,b1,acc[1][1]); acc[1][2]=fmaf(a1,b2,acc[1][2]); acc[1][3]=fmaf(a1,b3,acc[1][3]);
      acc[2][0]=fmaf(a2,b0,acc[2][0]); acc[2][1]=fmaf(a2,b1,acc[2][1]); acc[2][2]=fmaf(a2,b2,acc[2][2]); acc[2][3]=fmaf(a2,b3,acc[2][3]);
      acc[3][0]=fmaf(a3,b0,acc[3][0]); acc[3][1]=fmaf(a3,b1,acc[3][1]); acc[3][2]=fmaf(a3,b2,acc[3][2]); acc[3][3]=fmaf(a3,b3,acc[3][3]);
    }
    __syncthreads();
  }
  #pragma unroll
  for (int i = 0; i < 4; ++i) {
    int row = m0 + ty*4 + i;
    float4 v = make_float4(acc[i][0], acc[i][1], acc[i][2], acc[i][3]);
    int c = tx * 4;
    if (n0 < 512)      *(float4*)(rW1 + (size_t)row*512 + n0 + c)        = v;
    else if (n0 < 768) *(float4*)(rWf + (size_t)row*256 + (n0-512) + c)  = v;
    else               *(float4*)(rWi + (size_t)row*256 + (n0-768) + c)  = v;
  }
}

// ---------- per step: MEGA fused gemm1+gemm2 (one block per batch, 512 thr) ----------
// Phase 1: A2 = gelu(Ft@W1 + rW1 + b1) -> LDS; gates kept packed in REGISTERS.
// Phase 2: O = A2ls @ W2t; epilogue applies gates; writes Fout + Fbf. No global A2/G.
__global__ __launch_bounds__(512) void k_mega(
    const unsigned short* __restrict__ Fb_all, int bcast,
    const unsigned short* __restrict__ B1t,   // [1024][256] bf16
    const unsigned short* __restrict__ W2t,   // [256][512]  bf16
    const float* __restrict__ rW1, const float* __restrict__ b1,
    const float* __restrict__ rWf, const float* __restrict__ bfv,
    const float* __restrict__ rWi, const float* __restrict__ biv,
    const float* __restrict__ b2,  const float* __restrict__ rr,
    const float* __restrict__ Fprev, const float* __restrict__ FT,
    float* __restrict__ Fout, unsigned short* __restrict__ Fbf)
{
  __shared__ __align__(16) short A2ls[64*520];     // 66560 B (phase0: Fs stride 264)
  __shared__ __align__(16) short Sbuf[2*64*264];   // 67584 B (phase1 dbuf / phase2 Wst stride 520)
  int b = blockIdx.x, tid = threadIdx.x;
  int w = tid >> 6, lane = tid & 63, lr = lane & 15, lh = lane >> 4;
  int wm = w >> 2, wn = w & 3;     // 2x4 wave grid; wave tile 32 rows x 16 cols

  // ---- phase 0: stage F (as Fs in A2ls, stride 264) + B1t chunk 0
  const unsigned short* Fsrc = bcast ? Fb_all : (Fb_all + (size_t)b * 64 * 256);
  #pragma unroll
  for (int p = 0; p < 4; ++p) {
    int idx = (p*512 + tid) * 8;
    int row = idx >> 8, col = idx & 255;
    *(float4*)&A2ls[row*264 + col] = *(const float4*)&Fsrc[idx];
    *(float4*)&Sbuf[row*264 + col] = *(const float4*)&B1t[idx];
  }
  __syncthreads();
  short8v afr0[8], afr1[8];
  #pragma unroll
  for (int ks = 0; ks < 8; ++ks) {
    afr0[ks] = *(const short8v*)&A2ls[(wm*32 + lr)*264      + ks*32 + lh*8];
    afr1[ks] = *(const short8v*)&A2ls[(wm*32 + 16 + lr)*264 + ks*32 + lh*8];
  }
  __syncthreads();   // all afr reads done before A2ls is overwritten

  unsigned int fgp[4][4], igp[4][4];

  // ---- phase 1: 16 chunks of 64 cols over B1t (fully unrolled: static gate idx)
  #pragma unroll
  for (int c = 0; c < 16; ++c) {
    float4 pf[4];
    if (c < 15) {
      const unsigned short* src = B1t + (size_t)(c+1) * 64 * 256;
      #pragma unroll
      for (int p = 0; p < 4; ++p) pf[p] = *(const float4*)&src[(p*512 + tid)*8];
    }
    f32x4 acc0 = {0.f,0.f,0.f,0.f}, acc1 = {0.f,0.f,0.f,0.f};
    const short* Bb = &Sbuf[(c & 1) * 16896];
    #pragma unroll
    for (int ks = 0; ks < 8; ++ks) {
      short8v bf_ = *(const short8v*)&Bb[(wn*16 + lr)*264 + ks*32 + lh*8];
      acc0 = __builtin_amdgcn_mfma_f32_16x16x32_bf16(afr0[ks], bf_, acc0, 0, 0, 0);
      acc1 = __builtin_amdgcn_mfma_f32_16x16x32_bf16(afr1[ks], bf_, acc1, 0, 0, 0);
    }
    int col = c*64 + wn*16 + lr;
    if (c < 8) {
      float add = rW1[(size_t)b*512 + col] + b1[col];
      #pragma unroll
      for (int r = 0; r < 4; ++r) {
        int row0 = wm*32 + lh*4 + r;
        A2ls[row0*520 + col]      = f2bf(gelu_f(acc0[r] + add));
        A2ls[(row0+16)*520 + col] = f2bf(gelu_f(acc1[r] + add));
      }
    } else if (c < 12) {
      int cc = col - 512;
      float add = rWf[(size_t)b*256 + cc] + bfv[cc];
      #pragma unroll
      for (int r = 0; r < 4; ++r)
        fgp[c-8][r] = (((unsigned int)f2bf(sigmoid_f(add + tanh_fast(acc1[r])))) << 16)
                    |  (unsigned int)f2bf(sigmoid_f(add + tanh_fast(acc0[r])));
    } else {
      int cc = col - 768;
      float add = rWi[(size_t)b*256 + cc] + biv[cc];
      #pragma unroll
      for (int r = 0; r < 4; ++r)
        igp[c-12][r] = (((unsigned int)f2bf(sigmoid_f(add + tanh_fast(acc1[r])))) << 16)
                     |  (unsigned int)f2bf(sigmoid_f(add + tanh_fast(acc0[r])));
    }
    if (c < 15) {
      short* Bn = &Sbuf[((c+1) & 1) * 16896];
      #pragma unroll
      for (int p = 0; p < 4; ++p) {
        int idx = (p*512 + tid) * 8;
        int row = idx >> 8, colk = idx & 255;
        *(float4*)&Bn[row*264 + colk] = pf[p];
      }
    }
    __syncthreads();
  }

  // ---- phase 2: O = A2ls @ W2t, 4 chunks of 64 cols; gates from registers
  #pragma unroll
  for (int k = 0; k < 4; ++k) {
    const unsigned short* wsrc = W2t + (size_t)k * 64 * 512;
    #pragma unroll
    for (int p = 0; p < 8; ++p) {
      int idx = (p*512 + tid) * 8;
      int row = idx >> 9, colk = idx & 511;
      *(float4*)&Sbuf[row*520 + colk] = *(const float4*)&wsrc[idx];
    }
    __syncthreads();
    f32x4 o0 = {0.f,0.f,0.f,0.f}, o1 = {0.f,0.f,0.f,0.f};
    #pragma unroll
    for (int ks = 0; ks < 16; ++ks) {
      short8v a0 = *(const short8v*)&A2ls[(wm*32 + lr)*520      + ks*32 + lh*8];
      short8v a1 = *(const short8v*)&A2ls[(wm*32 + 16 + lr)*520 + ks*32 + lh*8];
      short8v bw = *(const short8v*)&Sbuf[(wn*16 + lr)*520      + ks*32 + lh*8];
      o0 = __builtin_amdgcn_mfma_f32_16x16x32_bf16(a0, bw, o0, 0, 0, 0);
      o1 = __builtin_amdgcn_mfma_f32_16x16x32_bf16(a1, bw, o1, 0, 0, 0);
    }
    int col = k*64 + wn*16 + lr;
    float b2c = b2[col], rv = rr[(size_t)b*256 + col];
    #pragma unroll
    for (int r = 0; r < 4; ++r) {
      int row = b*64 + wm*32 + lh*4 + r;
      float Ftv = bcast ? FT[(size_t)(row & 63)*256 + col] : Fprev[(size_t)row*256 + col];
      float fg = bfss((unsigned short)(fgp[k][r] & 0xffffu));
      float ig = bfss((unsigned short)(igp[k][r] & 0xffffu));
      float ftld = o0[r] + b2c + Ftv + rv;
      float ov = fg * Ftv + ig * tanh_fast(ftld);
      Fout[(size_t)row*256 + col] = ov;
      Fbf[(size_t)row*256 + col] = f2bf(ov);
      int row2 = row + 16;
      float Ftv2 = bcast ? FT[(size_t)(row2 & 63)*256 + col] : Fprev[(size_t)row2*256 + col];
      float fg2 = bfss((unsigned short)(fgp[k][r] >> 16));
      float ig2 = bfss((unsigned short)(igp[k][r] >> 16));
      float ftld2 = o1[r] + b2c + Ftv2 + rv;
      float ov2 = fg2 * Ftv2 + ig2 * tanh_fast(ftld2);
      Fout[(size_t)row2*256 + col] = ov2;
      Fbf[(size_t)row2*256 + col] = f2bf(ov2);
    }
    if (k < 3) __syncthreads();
  }
}

// ---------- host ----------
extern "C" void kernel_launch(void* const* d_in, const int* in_sizes, int n_in,
                              void* d_out, int out_size, void* d_ws, size_t ws_size,
                              hipStream_t stream)
{
  (void)in_sizes; (void)n_in; (void)out_size; (void)ws_size;
  const float* wsi  = (const float*)d_in[0];
  const float* gen  = (const float*)d_in[1];
  const float* FT   = (const float*)d_in[2];
  const float* W_lr = (const float*)d_in[3];
  const float* b_lr = (const float*)d_in[4];
  const float* W_g  = (const float*)d_in[5];
  const float* b_g  = (const float*)d_in[6];
  const float* WqI  = (const float*)d_in[7];
  const float* WqG  = (const float*)d_in[8];
  const float* WkI  = (const float*)d_in[9];
  const float* WkG  = (const float*)d_in[10];
  const float* WvI  = (const float*)d_in[11];
  const float* WvG  = (const float*)d_in[12];
  const float* W1   = (const float*)d_in[13];
  const float* b1   = (const float*)d_in[14];
  const float* W2   = (const float*)d_in[15];
  const float* b2   = (const float*)d_in[16];
  const float* Wf   = (const float*)d_in[17];
  const float* bf   = (const float*)d_in[18];
  const float* Wi   = (const float*)d_in[19];
  const float* bi   = (const float*)d_in[20];
  const float* Vf   = (const float*)d_in[21];
  const float* Vi   = (const float*)d_in[22];
  const float* a_p  = (const float*)d_in[23];
  const float* b_p  = (const float*)d_in[24];

  float* out = (float*)d_out;
  float* ws  = (float*)d_ws;
  // fp32 region
  float* rr    = ws;                    // 256*256
  float* rW1   = rr    + 65536;         // 256*512
  float* rWf   = rW1   + 131072;
  float* rWi   = rWf   + 65536;
  float* qIp   = rWi   + 65536;
  float* qGp   = qIp   + 65536;
  float* lrf   = qGp   + 65536;         // 256*512
  float* gf    = lrf   + 131072;
  float* QI    = gf    + 131072;
  float* QG    = QI    + 65536;
  float* WkIt  = QG    + 65536;
  float* WkGt  = WkIt  + 65536;
  float* ftbI  = WkGt  + 65536;         // 256*256
  float* ftbG  = ftbI  + 65536;
  float* rt    = ftbG  + 65536;         // 256*1024
  // bf16 region
  unsigned short* Fbf  = (unsigned short*)(rt + 262144);   // 16384*256
  unsigned short* FTbf = Fbf  + 4194304;                   // 64*256
  unsigned short* B1t  = FTbf + 16384;                     // 1024*256
  unsigned short* W2t  = B1t  + 262144;                    // 256*512

  k_convert<<<2112, 256, 0, stream>>>(W1, Vf, Vi, W2, FT, WkI, WkG,
                                      B1t, W2t, FTbf, WkIt, WkGt);
  k_pre_lin<<<32, 256, 0, stream>>>(wsi, gen, W_lr, b_lr, W_g, b_g, a_p, b_p, lrf, gf);
  k_pre_q<<<32, 256, 0, stream>>>(lrf, gf, WqI, WqG, QI, QG);
  k_pre_qp<<<32, 256, 0, stream>>>(QI, QG, WkIt, WkGt, qIp, qGp);

  // out[j] = F_{8-j}; step st produces F_{st+1} -> slot 7-st.
  const float* Fcur = nullptr;
  int bcast = 1;
  for (int st = 0; st < T_; ++st) {
    float* Fnext = out + (size_t)(7 - st) * NROW * D_;
    k_ftbar<<<256, 256, 0, stream>>>(bcast ? FTbf : Fbf, bcast, qIp, qGp, ftbI, ftbG);
    k_rt<<<64, 256, 0, stream>>>(ftbI, ftbG, WvI, WvG, rt);
    k_defuzz<<<256, 256, 0, stream>>>(rt, a_p, b_p, rr);
    k_rW<<<64, 256, 0, stream>>>(rr, W1, Wf, Wi, rW1, rWf, rWi);
    k_mega<<<256, 512, 0, stream>>>(bcast ? FTbf : Fbf, bcast, B1t, W2t,
                                    rW1, b1, rWf, bf, rWi, bi, b2, rr,
                                    Fcur, FT, Fnext, Fbf);
    Fcur = Fnext;
    bcast = 0;
  }
}

// Round 12
// 1065.122 us; speedup vs baseline: 1.4022x; 1.4022x over previous
//
#include <hip/hip_runtime.h>
#include <hip/hip_bf16.h>

// Problem constants
#define B_    256
#define K_    64
#define D_    256
#define T_    8
#define NROW  (B_*K_)

typedef short short8v __attribute__((ext_vector_type(8)));
typedef float f32x4  __attribute__((ext_vector_type(4)));

// ---------- device helpers ----------
__device__ __forceinline__ float fexp2(float x) { return __builtin_amdgcn_exp2f(x); }
__device__ __forceinline__ float flog2(float x) { return __builtin_amdgcn_logf(x); }

__device__ __forceinline__ float sigmoid_f(float x) {
  return 1.f / (1.f + fexp2(x * -1.4426950408889634f));
}
__device__ __forceinline__ float tanh_fast(float x) {
  float xc = fminf(fmaxf(x, -30.f), 30.f);
  float t = fexp2(xc * 2.8853900817779268f);   // e^(2x)
  return (t - 1.f) / (t + 1.f);
}
__device__ __forceinline__ float gelu_f(float x) {
  return 0.5f * x * (1.f + erff(x * 0.70710678118654752440f));
}
__device__ __forceinline__ unsigned short f2bf(float x) {
  __hip_bfloat16 h = __float2bfloat16(x);
  return *reinterpret_cast<unsigned short*>(&h);
}
__device__ __forceinline__ float bfss(unsigned short s) {
  return __uint_as_float(((unsigned int)s) << 16);
}
__device__ __forceinline__ float muS_f(float x, float a2, float b2) {
  float mid = 0.5f * (a2 + b2);
  float inv = 1.f / (b2 - a2 + 1e-12f);
  if (x > b2)  return 1.f;
  if (x > mid) { float u = (b2 - x) * inv; return 1.f - 2.f * u * u; }
  if (x > a2)  { float u = (x - a2) * inv; return 2.f * u * u; }
  return 0.f;
}
__device__ __forceinline__ float pow_abs(float z, float e2b) {
  return fexp2(e2b * flog2(fabsf(z)));
}
__device__ __forceinline__ float defuzz_one(float rb_, float rs_, float ab, float bb) {
  float e2b = 2.f * bb;
  float inv_ab = 1.f / ab;
  float cb = 4.f * tanh_fast(rb_);
  float num = 0.f, den = 0.f;
  #pragma unroll
  for (int j = 0; j < 41; ++j) {
    float gj = -4.f + 0.2f * (float)j;
    float mu = 1.f / (1.f + pow_abs((gj - cb) * inv_ab, e2b));
    num += gj * mu; den += mu;
  }
  float cenb = num / (den + 1e-12f);
  float cs = 4.f * tanh_fast(rs_);
  float as_ = fminf(fmaxf(cs - 1.f, -4.f), 4.f);
  float bs_ = fminf(fmaxf(cs + 1.f, -4.f), 4.f);
  num = 0.f; den = 0.f;
  {
    float mid = 0.5f * (as_ + bs_);
    float inv = 1.f / (bs_ - as_ + 1e-12f);
    #pragma unroll
    for (int j = 0; j < 41; ++j) {
      float gj = -4.f + 0.2f * (float)j;
      float mu;
      if (gj > bs_)      mu = 1.f;
      else if (gj > mid) { float u = (bs_ - gj) * inv; mu = 1.f - 2.f * u * u; }
      else if (gj > as_) { float u = (gj - as_) * inv; mu = 2.f * u * u; }
      else               mu = 0.f;
      num += gj * mu; den += mu;
    }
  }
  float cens = num / (den + 1e-12f);
  return 0.5f * cenb + 0.5f * cens;
}

// ---------- one-time: weight transposes / bf16 conversions ----------
__global__ __launch_bounds__(256) void k_convert(
    const float* __restrict__ W1, const float* __restrict__ Vf, const float* __restrict__ Vi,
    const float* __restrict__ W2, const float* __restrict__ FT,
    const float* __restrict__ WkI, const float* __restrict__ WkG,
    unsigned short* __restrict__ B1t, unsigned short* __restrict__ W2t,
    unsigned short* __restrict__ FTbf,
    float* __restrict__ WkIt, float* __restrict__ WkGt)
{
  int idx = blockIdx.x * 256 + threadIdx.x;
  if (idx < 262144) {
    int n = idx >> 8, k = idx & 255;
    float v = (n < 512) ? W1[(size_t)k*512 + n]
            : (n < 768) ? Vf[(size_t)k*256 + (n-512)]
                        : Vi[(size_t)k*256 + (n-768)];
    B1t[idx] = f2bf(v);
  } else if (idx < 393216) {
    int j = idx - 262144;
    int n = j >> 9, k = j & 511;
    W2t[j] = f2bf(W2[(size_t)k*256 + n]);
  } else if (idx < 409600) {
    int j = idx - 393216;
    FTbf[j] = f2bf(FT[j]);
  } else if (idx < 475136) {
    int j = idx - 409600;
    int k = j >> 8, n = j & 255;
    WkIt[j] = WkI[(size_t)n*256 + k];
  } else if (idx < 540672) {
    int j = idx - 475136;
    int k = j >> 8, n = j & 255;
    WkGt[j] = WkG[(size_t)n*256 + k];
  }
}

// ---------- precompute stage 1: lr/g linear + fuzzify ----------
__global__ __launch_bounds__(256) void k_pre_lin(
    const float* __restrict__ wsi, const float* __restrict__ gen,
    const float* __restrict__ W_lr, const float* __restrict__ b_lr,
    const float* __restrict__ W_g,  const float* __restrict__ b_g,
    const float* __restrict__ a_p,  const float* __restrict__ b_p,
    float* __restrict__ lrf, float* __restrict__ gf)
{
  int g_ix = blockIdx.x;
  int half = g_ix >> 4, tile = g_ix & 15;
  int bx = tile & 3, by = tile >> 2;
  int n0 = bx * 64, m0 = by * 64;
  const float* A    = half ? gen  : wsi;
  const float* Bm   = half ? W_g  : W_lr;
  const float* bias = half ? b_g  : b_lr;
  float* outp       = half ? gf   : lrf;
  int KK            = half ? 512  : 1024;
  float ab = fmaxf(a_p[0], 0.001f), bb = fmaxf(b_p[0], 0.001f);
  float e2b = 2.f * bb, inv_ab = 1.f / ab;

  __shared__ float As[16][64];
  __shared__ float Bs[16][64];
  int tid = threadIdx.x, tx = tid & 15, ty = tid >> 4;
  float acc[4][4] = {};
  int am = tid >> 2, ak = (tid & 3) * 4;
  int bk = tid >> 4, bn = (tid & 15) * 4;
  const float* arow = A + (size_t)(m0 + am) * KK;
  for (int k0 = 0; k0 < KK; k0 += 16) {
    float4 av = *(const float4*)(arow + k0 + ak);
    As[ak+0][am] = av.x; As[ak+1][am] = av.y; As[ak+2][am] = av.z; As[ak+3][am] = av.w;
    *(float4*)&Bs[bk][bn] = *(const float4*)(Bm + (size_t)(k0 + bk) * 256 + n0 + bn);
    __syncthreads();
    #pragma unroll
    for (int kk = 0; kk < 16; ++kk) {
      float a0 = As[kk][ty*4+0], a1 = As[kk][ty*4+1], a2 = As[kk][ty*4+2], a3 = As[kk][ty*4+3];
      float b0 = Bs[kk][tx*4+0], b1 = Bs[kk][tx*4+1], b2 = Bs[kk][tx*4+2], b3 = Bs[kk][tx*4+3];
      acc[0][0]=fmaf(a0,b0,acc[0][0]); acc[0][1]=fmaf(a0,b1,acc[0][1]); acc[0][2]=fmaf(a0,b2,acc[0][2]); acc[0][3]=fmaf(a0,b3,acc[0][3]);
      acc[1][0]=fmaf(a1,b0,acc[1][0]); acc[1][1]=fmaf(a1,b1,acc[1][1]); acc[1][2]=fmaf(a1,b2,acc[1][2]); acc[1][3]=fmaf(a1,b3,acc[1][3]);
      acc[2][0]=fmaf(a2,b0,acc[2][0]); acc[2][1]=fmaf(a2,b1,acc[2][1]); acc[2][2]=fmaf(a2,b2,acc[2][2]); acc[2][3]=fmaf(a2,b3,acc[2][3]);
      acc[3][0]=fmaf(a3,b0,acc[3][0]); acc[3][1]=fmaf(a3,b1,acc[3][1]); acc[3][2]=fmaf(a3,b2,acc[3][2]); acc[3][3]=fmaf(a3,b3,acc[3][3]);
    }
    __syncthreads();
  }
  #pragma unroll
  for (int i = 0; i < 4; ++i) {
    int row = m0 + ty*4 + i;
    #pragma unroll
    for (int j = 0; j < 4; ++j) {
      int col = n0 + tx*4 + j;
      float v = acc[i][j] + bias[col];
      float xs = 4.f * tanh_fast(v * 0.25f);
      outp[(size_t)row*512 + col]       = 1.f / (1.f + pow_abs(xs * inv_ab, e2b));
      outp[(size_t)row*512 + col + 256] = muS_f(xs, -1.f, 1.f);
    }
  }
}

// ---------- precompute stage 2: QI = lrf@WqI, QG = gf@WqG ----------
__global__ __launch_bounds__(256) void k_pre_q(
    const float* __restrict__ lrf, const float* __restrict__ gf,
    const float* __restrict__ WqI, const float* __restrict__ WqG,
    float* __restrict__ QI, float* __restrict__ QG)
{
  int g_ix = blockIdx.x;
  int half = g_ix >> 4, tile = g_ix & 15;
  int bx = tile & 3, by = tile >> 2;
  int n0 = bx * 64, m0 = by * 64;
  const float* A  = half ? gf  : lrf;
  const float* Bm = half ? WqG : WqI;
  float* outp     = half ? QG  : QI;

  __shared__ float As[16][64];
  __shared__ float Bs[16][64];
  int tid = threadIdx.x, tx = tid & 15, ty = tid >> 4;
  float acc[4][4] = {};
  int am = tid >> 2, ak = (tid & 3) * 4;
  int bk = tid >> 4, bn = (tid & 15) * 4;
  const float* arow = A + (size_t)(m0 + am) * 512;
  for (int k0 = 0; k0 < 512; k0 += 16) {
    float4 av = *(const float4*)(arow + k0 + ak);
    As[ak+0][am] = av.x; As[ak+1][am] = av.y; As[ak+2][am] = av.z; As[ak+3][am] = av.w;
    *(float4*)&Bs[bk][bn] = *(const float4*)(Bm + (size_t)(k0 + bk) * 256 + n0 + bn);
    __syncthreads();
    #pragma unroll
    for (int kk = 0; kk < 16; ++kk) {
      float a0 = As[kk][ty*4+0], a1 = As[kk][ty*4+1], a2 = As[kk][ty*4+2], a3 = As[kk][ty*4+3];
      float b0 = Bs[kk][tx*4+0], b1 = Bs[kk][tx*4+1], b2 = Bs[kk][tx*4+2], b3 = Bs[kk][tx*4+3];
      acc[0][0]=fmaf(a0,b0,acc[0][0]); acc[0][1]=fmaf(a0,b1,acc[0][1]); acc[0][2]=fmaf(a0,b2,acc[0][2]); acc[0][3]=fmaf(a0,b3,acc[0][3]);
      acc[1][0]=fmaf(a1,b0,acc[1][0]); acc[1][1]=fmaf(a1,b1,acc[1][1]); acc[1][2]=fmaf(a1,b2,acc[1][2]); acc[1][3]=fmaf(a1,b3,acc[1][3]);
      acc[2][0]=fmaf(a2,b0,acc[2][0]); acc[2][1]=fmaf(a2,b1,acc[2][1]); acc[2][2]=fmaf(a2,b2,acc[2][2]); acc[2][3]=fmaf(a2,b3,acc[2][3]);
      acc[3][0]=fmaf(a3,b0,acc[3][0]); acc[3][1]=fmaf(a3,b1,acc[3][1]); acc[3][2]=fmaf(a3,b2,acc[3][2]); acc[3][3]=fmaf(a3,b3,acc[3][3]);
    }
    __syncthreads();
  }
  #pragma unroll
  for (int i = 0; i < 4; ++i) {
    float4 v = make_float4(acc[i][0], acc[i][1], acc[i][2], acc[i][3]);
    *(float4*)(outp + (size_t)(m0 + ty*4 + i) * 256 + n0 + tx*4) = v;
  }
}

// ---------- precompute stage 3: qIp = QI@WkIt, qGp = QG@WkGt ----------
__global__ __launch_bounds__(256) void k_pre_qp(
    const float* __restrict__ QI, const float* __restrict__ QG,
    const float* __restrict__ WkIt, const float* __restrict__ WkGt,
    float* __restrict__ qIp, float* __restrict__ qGp)
{
  int g_ix = blockIdx.x;
  int half = g_ix >> 4, tile = g_ix & 15;
  int bx = tile & 3, by = tile >> 2;
  int n0 = bx * 64, m0 = by * 64;
  const float* A  = half ? QG   : QI;
  const float* Bm = half ? WkGt : WkIt;
  float* outp     = half ? qGp  : qIp;

  __shared__ float As[16][64];
  __shared__ float Bs[16][64];
  int tid = threadIdx.x, tx = tid & 15, ty = tid >> 4;
  float acc[4][4] = {};
  int am = tid >> 2, ak = (tid & 3) * 4;
  int bk = tid >> 4, bn = (tid & 15) * 4;
  const float* arow = A + (size_t)(m0 + am) * 256;
  for (int k0 = 0; k0 < 256; k0 += 16) {
    float4 av = *(const float4*)(arow + k0 + ak);
    As[ak+0][am] = av.x; As[ak+1][am] = av.y; As[ak+2][am] = av.z; As[ak+3][am] = av.w;
    *(float4*)&Bs[bk][bn] = *(const float4*)(Bm + (size_t)(k0 + bk) * 256 + n0 + bn);
    __syncthreads();
    #pragma unroll
    for (int kk = 0; kk < 16; ++kk) {
      float a0 = As[kk][ty*4+0], a1 = As[kk][ty*4+1], a2 = As[kk][ty*4+2], a3 = As[kk][ty*4+3];
      float b0 = Bs[kk][tx*4+0], b1 = Bs[kk][tx*4+1], b2 = Bs[kk][tx*4+2], b3 = Bs[kk][tx*4+3];
      acc[0][0]=fmaf(a0,b0,acc[0][0]); acc[0][1]=fmaf(a0,b1,acc[0][1]); acc[0][2]=fmaf(a0,b2,acc[0][2]); acc[0][3]=fmaf(a0,b3,acc[0][3]);
      acc[1][0]=fmaf(a1,b0,acc[1][0]); acc[1][1]=fmaf(a1,b1,acc[1][1]); acc[1][2]=fmaf(a1,b2,acc[1][2]); acc[1][3]=fmaf(a1,b3,acc[1][3]);
      acc[2][0]=fmaf(a2,b0,acc[2][0]); acc[2][1]=fmaf(a2,b1,acc[2][1]); acc[2][2]=fmaf(a2,b2,acc[2][2]); acc[2][3]=fmaf(a2,b3,acc[2][3]);
      acc[3][0]=fmaf(a3,b0,acc[3][0]); acc[3][1]=fmaf(a3,b1,acc[3][1]); acc[3][2]=fmaf(a3,b2,acc[3][2]); acc[3][3]=fmaf(a3,b3,acc[3][3]);
    }
    __syncthreads();
  }
  #pragma unroll
  for (int i = 0; i < 4; ++i) {
    float4 v = make_float4(acc[i][0], acc[i][1], acc[i][2], acc[i][3]);
    *(float4*)(outp + (size_t)(m0 + ty*4 + i) * 256 + n0 + tx*4) = v;
  }
}

// ---------- step 0 only: ftbar (scores+softmax+weighted-sum), one block per batch ----------
__global__ __launch_bounds__(256) void k_ftbar(
    const unsigned short* __restrict__ Fb_all, int bcast,
    const float* __restrict__ qIp, const float* __restrict__ qGp,
    float* __restrict__ ftbI, float* __restrict__ ftbG)
{
  __shared__ __align__(16) char smem[38912];
  int b = blockIdx.x, t = threadIdx.x;
  short* Fs  = (short*)smem;                  // [64][264] bf16
  float* qv  = (float*)(smem + 33792);        // [512]
  float* red = (float*)(smem + 35840);        // [512]
  float* prl = (float*)(smem + 37888);        // p [128]

  const unsigned short* Fsrc = bcast ? Fb_all : (Fb_all + (size_t)b * K_ * D_);
  #pragma unroll
  for (int i = 0; i < 8; ++i) {
    int sidx = (i * 256 + t) * 8;
    int row = sidx >> 8, col = sidx & 255;
    *(float4*)&Fs[row * 264 + col] = *(const float4*)&Fsrc[sidx];
  }
  qv[t]       = qIp[(size_t)b*256 + t];
  qv[256 + t] = qGp[(size_t)b*256 + t];
  __syncthreads();
  {
    int k = t & 63, part = t >> 6;
    const unsigned int* frow = (const unsigned int*)&Fs[k * 264 + part * 64];
    const float* q0 = qv + part * 64;
    const float* q1 = qv + 256 + part * 64;
    float s0 = 0.f, s1 = 0.f;
    #pragma unroll
    for (int d2 = 0; d2 < 32; ++d2) {
      unsigned int pr = frow[d2];
      float f0 = __uint_as_float(pr << 16);
      float f1 = __uint_as_float(pr & 0xffff0000u);
      s0 = fmaf(f1, q0[2*d2+1], fmaf(f0, q0[2*d2], s0));
      s1 = fmaf(f1, q1[2*d2+1], fmaf(f0, q1[2*d2], s1));
    }
    red[t] = s0; red[256 + t] = s1;
  }
  __syncthreads();
  if (t < 128) {
    int which = t >> 6, kk = t & 63;
    const float* rp = red + which * 256;
    float s = (rp[kk] + rp[64+kk] + rp[128+kk] + rp[192+kk]) * (1.f/16.f);
    float m = s;
    for (int off = 32; off; off >>= 1) m = fmaxf(m, __shfl_xor(m, off, 64));
    float e = fexp2((s - m) * 1.4426950408889634f);
    float sum = e;
    for (int off = 32; off; off >>= 1) sum += __shfl_xor(sum, off, 64);
    prl[which * 64 + kk] = e / sum;
  }
  __syncthreads();
  {
    float f0 = 0.f, f1 = 0.f;
    #pragma unroll 8
    for (int kk = 0; kk < 64; ++kk) {
      float fv = bfss((unsigned short)Fs[kk * 264 + t]);
      f0 = fmaf(prl[kk],      fv, f0);
      f1 = fmaf(prl[64 + kk], fv, f1);
    }
    ftbI[(size_t)b*256 + t] = f0;
    ftbG[(size_t)b*256 + t] = f1;
  }
}

// ---------- per step: rt = [ftbI@WvI | ftbG@WvG]  M=256 N=1024 K=256 ----------
__global__ __launch_bounds__(256) void k_rt(
    const float* __restrict__ ftbI, const float* __restrict__ ftbG,
    const float* __restrict__ WvI,  const float* __restrict__ WvG,
    float* __restrict__ rt)
{
  int bx = blockIdx.x & 15, by = blockIdx.x >> 4;
  int n0 = bx * 64, m0 = by * 64;
  const float* Ap = (n0 < 512) ? ftbI : ftbG;
  const float* Bp = (n0 < 512) ? WvI  : WvG;
  int nb = (n0 < 512) ? n0 : n0 - 512;
  __shared__ float As[16][64];
  __shared__ float Bs[16][64];
  int tid = threadIdx.x, tx = tid & 15, ty = tid >> 4;
  float acc[4][4] = {};
  int am = tid >> 2, ak = (tid & 3) * 4;
  int bk = tid >> 4, bn = (tid & 15) * 4;
  const float* arow = Ap + (size_t)(m0 + am) * 256;
  for (int k0 = 0; k0 < 256; k0 += 16) {
    float4 av = *(const float4*)(arow + k0 + ak);
    As[ak+0][am] = av.x; As[ak+1][am] = av.y; As[ak+2][am] = av.z; As[ak+3][am] = av.w;
    *(float4*)&Bs[bk][bn] = *(const float4*)(Bp + (size_t)(k0 + bk) * 512 + nb + bn);
    __syncthreads();
    #pragma unroll
    for (int kk = 0; kk < 16; ++kk) {
      float a0 = As[kk][ty*4+0], a1 = As[kk][ty*4+1], a2 = As[kk][ty*4+2], a3 = As[kk][ty*4+3];
      float b0 = Bs[kk][tx*4+0], b1 = Bs[kk][tx*4+1], b2 = Bs[kk][tx*4+2], b3 = Bs[kk][tx*4+3];
      acc[0][0]=fmaf(a0,b0,acc[0][0]); acc[0][1]=fmaf(a0,b1,acc[0][1]); acc[0][2]=fmaf(a0,b2,acc[0][2]); acc[0][3]=fmaf(a0,b3,acc[0][3]);
      acc[1][0]=fmaf(a1,b0,acc[1][0]); acc[1][1]=fmaf(a1,b1,acc[1][1]); acc[1][2]=fmaf(a1,b2,acc[1][2]); acc[1][3]=fmaf(a1,b3,acc[1][3]);
      acc[2][0]=fmaf(a2,b0,acc[2][0]); acc[2][1]=fmaf(a2,b1,acc[2][1]); acc[2][2]=fmaf(a2,b2,acc[2][2]); acc[2][3]=fmaf(a2,b3,acc[2][3]);
      acc[3][0]=fmaf(a3,b0,acc[3][0]); acc[3][1]=fmaf(a3,b1,acc[3][1]); acc[3][2]=fmaf(a3,b2,acc[3][2]); acc[3][3]=fmaf(a3,b3,acc[3][3]);
    }
    __syncthreads();
  }
  #pragma unroll
  for (int i = 0; i < 4; ++i) {
    float4 v = make_float4(acc[i][0], acc[i][1], acc[i][2], acc[i][3]);
    *(float4*)(rt + (size_t)(m0 + ty*4 + i) * 1024 + n0 + tx*4) = v;
  }
}

// ---------- per step: defuzzify -> r ----------
__global__ __launch_bounds__(256) void k_defuzz(
    const float* __restrict__ rt,
    const float* __restrict__ a_p, const float* __restrict__ b_p,
    float* __restrict__ r_out)
{
  int b = blockIdx.x, t = threadIdx.x;
  float ab = fmaxf(a_p[0], 0.001f), bb = fmaxf(b_p[0], 0.001f);
  const float* rb = rt + (size_t)b * 1024;
  float rI = defuzz_one(rb[t],       rb[256 + t], ab, bb);
  float rG = defuzz_one(rb[512 + t], rb[768 + t], ab, bb);
  r_out[(size_t)b*256 + t] = 0.5f * rI + 0.5f * rG;
}

// ---------- per step: rW = r @ [W1 | Wf | Wi]  M=256 N=1024 K=256 ----------
__global__ __launch_bounds__(256) void k_rW(
    const float* __restrict__ r,
    const float* __restrict__ W1, const float* __restrict__ Wf, const float* __restrict__ Wi,
    float* __restrict__ rW1, float* __restrict__ rWf, float* __restrict__ rWi)
{
  int bx = blockIdx.x & 15, by = blockIdx.x >> 4;
  int n0 = bx * 64, m0 = by * 64;
  const float* Bp; int ldb, nb;
  if (n0 < 512)      { Bp = W1; ldb = 512; nb = n0; }
  else if (n0 < 768) { Bp = Wf; ldb = 256; nb = n0 - 512; }
  else               { Bp = Wi; ldb = 256; nb = n0 - 768; }
  __shared__ float As[16][64];
  __shared__ float Bs[16][64];
  int tid = threadIdx.x, tx = tid & 15, ty = tid >> 4;
  float acc[4][4] = {};
  int am = tid >> 2, ak = (tid & 3) * 4;
  int bk = tid >> 4, bn = (tid & 15) * 4;
  const float* arow = r + (size_t)(m0 + am) * 256;
  for (int k0 = 0; k0 < 256; k0 += 16) {
    float4 av = *(const float4*)(arow + k0 + ak);
    As[ak+0][am] = av.x; As[ak+1][am] = av.y; As[ak+2][am] = av.z; As[ak+3][am] = av.w;
    *(float4*)&Bs[bk][bn] = *(const float4*)(Bp + (size_t)(k0 + bk) * ldb + nb + bn);
    __syncthreads();
    #pragma unroll
    for (int kk = 0; kk < 16; ++kk) {
      float a0 = As[kk][ty*4+0], a1 = As[kk][ty*4+1], a2 = As[kk][ty*4+2], a3 = As[kk][ty*4+3];
      float b0 = Bs[kk][tx*4+0], b1 = Bs[kk][tx*4+1], b2 = Bs[kk][tx*4+2], b3 = Bs[kk][tx*4+3];
      acc[0][0]=fmaf(a0,b0,acc[0][0]); acc[0][1]=fmaf(a0,b1,acc[0][1]); acc[0][2]=fmaf(a0,b2,acc[0][2]); acc[0][3]=fmaf(a0,b3,acc[0][3]);
      acc[1][0]=fmaf(a1,b0,acc[1][0]); acc[1][1]=fmaf(a1,b1,acc[1][1]); acc[1][2]=fmaf(a1,b2,acc[1][2]); acc[1][3]=fmaf(a1,b3,acc[1][3]);
      acc[2][0]=fmaf(a2,b0,acc[2][0]); acc[2][1]=fmaf(a2,b1,acc[2][1]); acc[2][2]=fmaf(a2,b2,acc[2][2]); acc[2][3]=fmaf(a2,b3,acc[2][3]);
      acc[3][0]=fmaf(a3,b0,acc[3][0]); acc[3][1]=fmaf(a3,b1,acc[3][1]); acc[3][2]=fmaf(a3,b2,acc[3][2]); acc[3][3]=fmaf(a3,b3,acc[3][3]);
    }
    __syncthreads();
  }
  #pragma unroll
  for (int i = 0; i < 4; ++i) {
    int row = m0 + ty*4 + i;
    float4 v = make_float4(acc[i][0], acc[i][1], acc[i][2], acc[i][3]);
    int c = tx * 4;
    if (n0 < 512)      *(float4*)(rW1 + (size_t)row*512 + n0 + c)        = v;
    else if (n0 < 768) *(float4*)(rWf + (size_t)row*256 + (n0-512) + c)  = v;
    else               *(float4*)(rWi + (size_t)row*256 + (n0-768) + c)  = v;
  }
}

// ---------- per step: GEMM1 persistent-row (block = batch b); A-frags from global ----------
__global__ __launch_bounds__(512) void k_g1(
    const unsigned short* __restrict__ Fb_all, int bcast,
    const unsigned short* __restrict__ B1t,
    const float* __restrict__ rW1, const float* __restrict__ b1,
    const float* __restrict__ rWf, const float* __restrict__ bfv,
    const float* __restrict__ rWi, const float* __restrict__ biv,
    unsigned short* __restrict__ A2, unsigned short* __restrict__ Gf, unsigned short* __restrict__ Gi)
{
  __shared__ __align__(16) short Bst[2][64*264];   // 67584 B -> 2 blocks/CU
  int b = blockIdx.x, tid = threadIdx.x;
  int w = tid >> 6, lane = tid & 63, lr = lane & 15, lh = lane >> 4;
  int wm = w >> 2, wn = w & 3;                     // wave tile: 32 rows x 16 cols

  const unsigned short* Fsrc = bcast ? Fb_all : (Fb_all + (size_t)b * 64 * 256);
  short8v afr0[8], afr1[8];
  #pragma unroll
  for (int ks = 0; ks < 8; ++ks) {
    afr0[ks] = *(const short8v*)&Fsrc[(size_t)(wm*32 + lr)*256      + ks*32 + lh*8];
    afr1[ks] = *(const short8v*)&Fsrc[(size_t)(wm*32 + 16 + lr)*256 + ks*32 + lh*8];
  }
  #pragma unroll
  for (int p = 0; p < 4; ++p) {
    int idx = (p*512 + tid) * 8;
    int row = idx >> 8, col = idx & 255;
    *(float4*)&Bst[0][row*264 + col] = *(const float4*)&B1t[idx];
  }
  __syncthreads();

  for (int c = 0; c < 16; ++c) {
    float4 pf[4];
    if (c < 15) {
      const unsigned short* src = B1t + (size_t)(c+1) * 16384;
      #pragma unroll
      for (int p = 0; p < 4; ++p) pf[p] = *(const float4*)&src[(p*512 + tid)*8];
    }
    f32x4 acc0 = {0.f,0.f,0.f,0.f}, acc1 = {0.f,0.f,0.f,0.f};
    const short* Bb = Bst[c & 1];
    #pragma unroll
    for (int ks = 0; ks < 8; ++ks) {
      short8v bf_ = *(const short8v*)&Bb[(wn*16 + lr)*264 + ks*32 + lh*8];
      acc0 = __builtin_amdgcn_mfma_f32_16x16x32_bf16(afr0[ks], bf_, acc0, 0, 0, 0);
      acc1 = __builtin_amdgcn_mfma_f32_16x16x32_bf16(afr1[ks], bf_, acc1, 0, 0, 0);
    }
    int col = c*64 + wn*16 + lr;
    if (col < 512) {
      float add = rW1[(size_t)b*512 + col] + b1[col];
      #pragma unroll
      for (int r = 0; r < 4; ++r) {
        int row0 = b*64 + wm*32 + lh*4 + r;
        A2[(size_t)row0*512 + col]      = f2bf(gelu_f(acc0[r] + add));
        A2[(size_t)(row0+16)*512 + col] = f2bf(gelu_f(acc1[r] + add));
      }
    } else if (col < 768) {
      int cc = col - 512;
      float add = rWf[(size_t)b*256 + cc] + bfv[cc];
      #pragma unroll
      for (int r = 0; r < 4; ++r) {
        int row0 = b*64 + wm*32 + lh*4 + r;
        Gf[(size_t)row0*256 + cc]      = f2bf(sigmoid_f(add + tanh_fast(acc0[r])));
        Gf[(size_t)(row0+16)*256 + cc] = f2bf(sigmoid_f(add + tanh_fast(acc1[r])));
      }
    } else {
      int cc = col - 768;
      float add = rWi[(size_t)b*256 + cc] + biv[cc];
      #pragma unroll
      for (int r = 0; r < 4; ++r) {
        int row0 = b*64 + wm*32 + lh*4 + r;
        Gi[(size_t)row0*256 + cc]      = f2bf(sigmoid_f(add + tanh_fast(acc0[r])));
        Gi[(size_t)(row0+16)*256 + cc] = f2bf(sigmoid_f(add + tanh_fast(acc1[r])));
      }
    }
    if (c < 15) {
      short* Bn = Bst[(c+1) & 1];
      #pragma unroll
      for (int p = 0; p < 4; ++p) {
        int idx = (p*512 + tid) * 8;
        int row = idx >> 8, colk = idx & 255;
        *(float4*)&Bn[row*264 + colk] = pf[p];
      }
      __syncthreads();
    }
  }
}

// ---------- per step: GEMM2 persistent-row + gate epilogue + INLINE ftbar(next) ----------
__global__ __launch_bounds__(512) void k_g2(
    const unsigned short* __restrict__ A2, const unsigned short* __restrict__ W2t,
    const float* __restrict__ b2,
    const float* __restrict__ Fprev, const float* __restrict__ FT, int bcast,
    const float* __restrict__ rr,
    const unsigned short* __restrict__ Gf, const unsigned short* __restrict__ Gi,
    float* __restrict__ Fout, unsigned short* __restrict__ Fbf,
    const float* __restrict__ qIp, const float* __restrict__ qGp,
    float* __restrict__ ftbI, float* __restrict__ ftbG, int do_ftbar)
{
  __shared__ __align__(16) char smem[66560];      // Wst dbuf 66560 B -> 2 blocks/CU
  short (*Wst)[32*520] = (short (*)[32*520])smem;
  int b = blockIdx.x, tid = threadIdx.x;
  int w = tid >> 6, lane = tid & 63, lr = lane & 15, lh = lane >> 4;
  int wm = w >> 1, wn = w & 1;                    // wave tile: 16 rows x 16 cols

  short8v afr[16];
  #pragma unroll
  for (int ks = 0; ks < 16; ++ks)
    afr[ks] = *(const short8v*)&A2[(size_t)(b*64 + wm*16 + lr)*512 + ks*32 + lh*8];

  #pragma unroll
  for (int p = 0; p < 4; ++p) {
    int idx = (p*512 + tid) * 8;
    int row = idx >> 9, col = idx & 511;
    *(float4*)&Wst[0][row*520 + col] = *(const float4*)&W2t[idx];
  }
  __syncthreads();

  for (int c = 0; c < 8; ++c) {
    float4 pf[4];
    if (c < 7) {
      const unsigned short* src = W2t + (size_t)(c+1) * 16384;
      #pragma unroll
      for (int p = 0; p < 4; ++p) pf[p] = *(const float4*)&src[(p*512 + tid)*8];
    }
    f32x4 acc = {0.f,0.f,0.f,0.f};
    const short* Wb = Wst[c & 1];
    #pragma unroll
    for (int ks = 0; ks < 16; ++ks) {
      short8v bw = *(const short8v*)&Wb[(wn*16 + lr)*520 + ks*32 + lh*8];
      acc = __builtin_amdgcn_mfma_f32_16x16x32_bf16(afr[ks], bw, acc, 0, 0, 0);
    }
    int col = c*32 + wn*16 + lr;
    float b2c = b2[col], rv = rr[(size_t)b*256 + col];
    #pragma unroll
    for (int r = 0; r < 4; ++r) {
      int row = b*64 + wm*16 + lh*4 + r;
      float Ftv = bcast ? FT[(size_t)(row & 63)*256 + col]
                        : Fprev[(size_t)row*256 + col];
      float ftld = acc[r] + b2c + Ftv + rv;
      float fg = bfss(Gf[(size_t)row*256 + col]);
      float ig = bfss(Gi[(size_t)row*256 + col]);
      float ov = fg * Ftv + ig * tanh_fast(ftld);
      Fout[(size_t)row*256 + col] = ov;
      Fbf[(size_t)row*256 + col] = f2bf(ov);
    }
    if (c < 7) {
      short* Wn = Wst[(c+1) & 1];
      #pragma unroll
      for (int p = 0; p < 4; ++p) {
        int idx = (p*512 + tid) * 8;
        int row = idx >> 9, colk = idx & 511;
        *(float4*)&Wn[row*520 + colk] = pf[p];
      }
      __syncthreads();
    }
  }

  if (!do_ftbar) return;
  __syncthreads();   // drain Fbf stores (barrier implies vmcnt(0)); Wst no longer needed

  // ---- inline ftbar for next step (batch b), 512 threads: t<256 -> I, t>=256 -> G
  short* Fs  = (short*)smem;                 // [64][264] bf16 (33792 B)
  float* qv  = (float*)(smem + 33792);       // [512]
  float* red = (float*)(smem + 35840);       // [2][256]
  float* prl = (float*)(smem + 37888);       // p [128]
  int t = tid;
  const unsigned short* Fsrc = Fbf + (size_t)b * 64 * 256;
  #pragma unroll
  for (int i = 0; i < 4; ++i) {
    int sidx = (i * 512 + t) * 8;
    int row = sidx >> 8, col = sidx & 255;
    *(float4*)&Fs[row * 264 + col] = *(const float4*)&Fsrc[sidx];
  }
  if (t < 256) qv[t] = qIp[(size_t)b*256 + t];
  else         qv[t] = qGp[(size_t)b*256 + (t - 256)];
  __syncthreads();
  {
    int which = t >> 8, tt = t & 255;
    int k = tt & 63, part = tt >> 6;
    const unsigned int* frow = (const unsigned int*)&Fs[k * 264 + part * 64];
    const float* q0 = qv + which*256 + part * 64;
    float s0 = 0.f;
    #pragma unroll
    for (int d2 = 0; d2 < 32; ++d2) {
      unsigned int pr = frow[d2];
      float f0 = __uint_as_float(pr << 16);
      float f1 = __uint_as_float(pr & 0xffff0000u);
      s0 = fmaf(f1, q0[2*d2+1], fmaf(f0, q0[2*d2], s0));
    }
    red[which*256 + tt] = s0;
  }
  __syncthreads();
  if (t < 128) {
    int which = t >> 6, kk = t & 63;
    const float* rp = red + which * 256;
    float s = (rp[kk] + rp[64+kk] + rp[128+kk] + rp[192+kk]) * (1.f/16.f);
    float m = s;
    for (int off = 32; off; off >>= 1) m = fmaxf(m, __shfl_xor(m, off, 64));
    float e = fexp2((s - m) * 1.4426950408889634f);
    float sum = e;
    for (int off = 32; off; off >>= 1) sum += __shfl_xor(sum, off, 64);
    prl[which * 64 + kk] = e / sum;
  }
  __syncthreads();
  {
    int which = t >> 8, tt = t & 255;
    const float* pp = prl + which * 64;
    float f0 = 0.f;
    #pragma unroll 8
    for (int kk = 0; kk < 64; ++kk)
      f0 = fmaf(pp[kk], bfss((unsigned short)Fs[kk * 264 + tt]), f0);
    if (which == 0) ftbI[(size_t)b*256 + tt] = f0;
    else            ftbG[(size_t)b*256 + tt] = f0;
  }
}

// ---------- host ----------
extern "C" void kernel_launch(void* const* d_in, const int* in_sizes, int n_in,
                              void* d_out, int out_size, void* d_ws, size_t ws_size,
                              hipStream_t stream)
{
  (void)in_sizes; (void)n_in; (void)out_size; (void)ws_size;
  const float* wsi  = (const float*)d_in[0];
  const float* gen  = (const float*)d_in[1];
  const float* FT   = (const float*)d_in[2];
  const float* W_lr = (const float*)d_in[3];
  const float* b_lr = (const float*)d_in[4];
  const float* W_g  = (const float*)d_in[5];
  const float* b_g  = (const float*)d_in[6];
  const float* WqI  = (const float*)d_in[7];
  const float* WqG  = (const float*)d_in[8];
  const float* WkI  = (const float*)d_in[9];
  const float* WkG  = (const float*)d_in[10];
  const float* WvI  = (const float*)d_in[11];
  const float* WvG  = (const float*)d_in[12];
  const float* W1   = (const float*)d_in[13];
  const float* b1   = (const float*)d_in[14];
  const float* W2   = (const float*)d_in[15];
  const float* b2   = (const float*)d_in[16];
  const float* Wf   = (const float*)d_in[17];
  const float* bf   = (const float*)d_in[18];
  const float* Wi   = (const float*)d_in[19];
  const float* bi   = (const float*)d_in[20];
  const float* Vf   = (const float*)d_in[21];
  const float* Vi   = (const float*)d_in[22];
  const float* a_p  = (const float*)d_in[23];
  const float* b_p  = (const float*)d_in[24];

  float* out = (float*)d_out;
  float* ws  = (float*)d_ws;
  // fp32 region
  float* rr    = ws;                    // 256*256
  float* rW1   = rr    + 65536;         // 256*512
  float* rWf   = rW1   + 131072;
  float* rWi   = rWf   + 65536;
  float* qIp   = rWi   + 65536;
  float* qGp   = qIp   + 65536;
  float* lrf   = qGp   + 65536;         // 256*512
  float* gf    = lrf   + 131072;
  float* QI    = gf    + 131072;
  float* QG    = QI    + 65536;
  float* WkIt  = QG    + 65536;
  float* WkGt  = WkIt  + 65536;
  float* ftbI  = WkGt  + 65536;         // 256*256
  float* ftbG  = ftbI  + 65536;
  float* rt    = ftbG  + 65536;         // 256*1024
  // bf16 region
  unsigned short* A2   = (unsigned short*)(rt + 262144);   // 16384*512
  unsigned short* Gfb  = A2   + 8388608;                   // 16384*256
  unsigned short* Gib  = Gfb  + 4194304;                   // 16384*256
  unsigned short* Fbf  = Gib  + 4194304;                   // 16384*256
  unsigned short* FTbf = Fbf  + 4194304;                   // 64*256
  unsigned short* B1t  = FTbf + 16384;                     // 1024*256
  unsigned short* W2t  = B1t  + 262144;                    // 256*512

  k_convert<<<2112, 256, 0, stream>>>(W1, Vf, Vi, W2, FT, WkI, WkG,
                                      B1t, W2t, FTbf, WkIt, WkGt);
  k_pre_lin<<<32, 256, 0, stream>>>(wsi, gen, W_lr, b_lr, W_g, b_g, a_p, b_p, lrf, gf);
  k_pre_q<<<32, 256, 0, stream>>>(lrf, gf, WqI, WqG, QI, QG);
  k_pre_qp<<<32, 256, 0, stream>>>(QI, QG, WkIt, WkGt, qIp, qGp);

  // out[j] = F_{8-j}; step st produces F_{st+1} -> slot 7-st.
  const float* Fcur = nullptr;
  int bcast = 1;
  for (int st = 0; st < T_; ++st) {
    float* Fnext = out + (size_t)(7 - st) * NROW * D_;
    if (st == 0)
      k_ftbar<<<256, 256, 0, stream>>>(FTbf, 1, qIp, qGp, ftbI, ftbG);
    k_rt<<<64, 256, 0, stream>>>(ftbI, ftbG, WvI, WvG, rt);
    k_defuzz<<<256, 256, 0, stream>>>(rt, a_p, b_p, rr);
    k_rW<<<64, 256, 0, stream>>>(rr, W1, Wf, Wi, rW1, rWf, rWi);
    k_g1<<<256, 512, 0, stream>>>(bcast ? FTbf : Fbf, bcast, B1t,
                                  rW1, b1, rWf, bf, rWi, bi, A2, Gfb, Gib);
    k_g2<<<256, 512, 0, stream>>>(A2, W2t, b2, Fcur, FT, bcast, rr,
                                  Gfb, Gib, Fnext, Fbf,
                                  qIp, qGp, ftbI, ftbG, (st < 7) ? 1 : 0);
    Fcur = Fnext;
    bcast = 0;
  }
}

// Round 13
// 870.304 us; speedup vs baseline: 1.7161x; 1.2239x over previous
//
#include <hip/hip_runtime.h>
#include <hip/hip_bf16.h>

// Problem constants
#define B_    256
#define K_    64
#define D_    256
#define T_    8
#define NROW  (B_*K_)

typedef short short8v __attribute__((ext_vector_type(8)));
typedef float f32x4  __attribute__((ext_vector_type(4)));

// ---------- device helpers ----------
__device__ __forceinline__ float fexp2(float x) { return __builtin_amdgcn_exp2f(x); }
__device__ __forceinline__ float flog2(float x) { return __builtin_amdgcn_logf(x); }

__device__ __forceinline__ float sigmoid_f(float x) {
  return 1.f / (1.f + fexp2(x * -1.4426950408889634f));
}
__device__ __forceinline__ float tanh_fast(float x) {
  float xc = fminf(fmaxf(x, -30.f), 30.f);
  float t = fexp2(xc * 2.8853900817779268f);   // e^(2x)
  return (t - 1.f) / (t + 1.f);
}
__device__ __forceinline__ float gelu_f(float x) {
  return 0.5f * x * (1.f + erff(x * 0.70710678118654752440f));
}
__device__ __forceinline__ unsigned short f2bf(float x) {
  __hip_bfloat16 h = __float2bfloat16(x);
  return *reinterpret_cast<unsigned short*>(&h);
}
__device__ __forceinline__ float bfss(unsigned short s) {
  return __uint_as_float(((unsigned int)s) << 16);
}
__device__ __forceinline__ float muS_f(float x, float a2, float b2) {
  float mid = 0.5f * (a2 + b2);
  float inv = 1.f / (b2 - a2 + 1e-12f);
  if (x > b2)  return 1.f;
  if (x > mid) { float u = (b2 - x) * inv; return 1.f - 2.f * u * u; }
  if (x > a2)  { float u = (x - a2) * inv; return 2.f * u * u; }
  return 0.f;
}
__device__ __forceinline__ float pow_abs(float z, float e2b) {
  return fexp2(e2b * flog2(fabsf(z)));
}
__device__ __forceinline__ float defuzz_one(float rb_, float rs_, float ab, float bb) {
  float e2b = 2.f * bb;
  float inv_ab = 1.f / ab;
  float cb = 4.f * tanh_fast(rb_);
  float num = 0.f, den = 0.f;
  #pragma unroll
  for (int j = 0; j < 41; ++j) {
    float gj = -4.f + 0.2f * (float)j;
    float mu = 1.f / (1.f + pow_abs((gj - cb) * inv_ab, e2b));
    num += gj * mu; den += mu;
  }
  float cenb = num / (den + 1e-12f);
  float cs = 4.f * tanh_fast(rs_);
  float as_ = fminf(fmaxf(cs - 1.f, -4.f), 4.f);
  float bs_ = fminf(fmaxf(cs + 1.f, -4.f), 4.f);
  num = 0.f; den = 0.f;
  {
    float mid = 0.5f * (as_ + bs_);
    float inv = 1.f / (bs_ - as_ + 1e-12f);
    #pragma unroll
    for (int j = 0; j < 41; ++j) {
      float gj = -4.f + 0.2f * (float)j;
      float mu;
      if (gj > bs_)      mu = 1.f;
      else if (gj > mid) { float u = (bs_ - gj) * inv; mu = 1.f - 2.f * u * u; }
      else if (gj > as_) { float u = (gj - as_) * inv; mu = 2.f * u * u; }
      else               mu = 0.f;
      num += gj * mu; den += mu;
    }
  }
  float cens = num / (den + 1e-12f);
  return 0.5f * cenb + 0.5f * cens;
}

// ---------- one-time: weight transposes / bf16 conversions ----------
__global__ __launch_bounds__(256) void k_convert(
    const float* __restrict__ W1, const float* __restrict__ Vf, const float* __restrict__ Vi,
    const float* __restrict__ W2, const float* __restrict__ FT,
    const float* __restrict__ WkI, const float* __restrict__ WkG,
    const float* __restrict__ WvI, const float* __restrict__ WvG,
    const float* __restrict__ Wf,  const float* __restrict__ Wi,
    unsigned short* __restrict__ B1t, unsigned short* __restrict__ W2t,
    unsigned short* __restrict__ FTbf,
    float* __restrict__ WkIt, float* __restrict__ WkGt,
    unsigned short* __restrict__ Wv2, unsigned short* __restrict__ WB)
{
  int idx = blockIdx.x * 256 + threadIdx.x;
  if (idx < 262144) {
    int n = idx >> 8, k = idx & 255;
    float v = (n < 512) ? W1[(size_t)k*512 + n]
            : (n < 768) ? Vf[(size_t)k*256 + (n-512)]
                        : Vi[(size_t)k*256 + (n-768)];
    B1t[idx] = f2bf(v);
  } else if (idx < 393216) {
    int j = idx - 262144;
    int n = j >> 9, k = j & 511;
    W2t[j] = f2bf(W2[(size_t)k*256 + n]);
  } else if (idx < 409600) {
    int j = idx - 393216;
    FTbf[j] = f2bf(FT[j]);
  } else if (idx < 475136) {
    int j = idx - 409600;
    int k = j >> 8, n = j & 255;
    WkIt[j] = WkI[(size_t)n*256 + k];
  } else if (idx < 540672) {
    int j = idx - 475136;
    int k = j >> 8, n = j & 255;
    WkGt[j] = WkG[(size_t)n*256 + k];
  } else if (idx < 802816) {
    int j = idx - 540672;           // Wv2[d][c]: c<512 -> WvI, else WvG
    int d = j >> 10, c = j & 1023;
    float v = (c < 512) ? WvI[(size_t)d*512 + c] : WvG[(size_t)d*512 + (c-512)];
    Wv2[j] = f2bf(v);
  } else if (idx < 1064960) {
    int j = idx - 802816;           // WB[d][c]: W1 | Wf | Wi
    int d = j >> 10, c = j & 1023;
    float v = (c < 512) ? W1[(size_t)d*512 + c]
            : (c < 768) ? Wf[(size_t)d*256 + (c-512)]
                        : Wi[(size_t)d*256 + (c-768)];
    WB[j] = f2bf(v);
  }
}

// ---------- precompute stage 1: lr/g linear + fuzzify ----------
__global__ __launch_bounds__(256) void k_pre_lin(
    const float* __restrict__ wsi, const float* __restrict__ gen,
    const float* __restrict__ W_lr, const float* __restrict__ b_lr,
    const float* __restrict__ W_g,  const float* __restrict__ b_g,
    const float* __restrict__ a_p,  const float* __restrict__ b_p,
    float* __restrict__ lrf, float* __restrict__ gf)
{
  int g_ix = blockIdx.x;
  int half = g_ix >> 4, tile = g_ix & 15;
  int bx = tile & 3, by = tile >> 2;
  int n0 = bx * 64, m0 = by * 64;
  const float* A    = half ? gen  : wsi;
  const float* Bm   = half ? W_g  : W_lr;
  const float* bias = half ? b_g  : b_lr;
  float* outp       = half ? gf   : lrf;
  int KK            = half ? 512  : 1024;
  float ab = fmaxf(a_p[0], 0.001f), bb = fmaxf(b_p[0], 0.001f);
  float e2b = 2.f * bb, inv_ab = 1.f / ab;

  __shared__ float As[16][64];
  __shared__ float Bs[16][64];
  int tid = threadIdx.x, tx = tid & 15, ty = tid >> 4;
  float acc[4][4] = {};
  int am = tid >> 2, ak = (tid & 3) * 4;
  int bk = tid >> 4, bn = (tid & 15) * 4;
  const float* arow = A + (size_t)(m0 + am) * KK;
  for (int k0 = 0; k0 < KK; k0 += 16) {
    float4 av = *(const float4*)(arow + k0 + ak);
    As[ak+0][am] = av.x; As[ak+1][am] = av.y; As[ak+2][am] = av.z; As[ak+3][am] = av.w;
    *(float4*)&Bs[bk][bn] = *(const float4*)(Bm + (size_t)(k0 + bk) * 256 + n0 + bn);
    __syncthreads();
    #pragma unroll
    for (int kk = 0; kk < 16; ++kk) {
      float a0 = As[kk][ty*4+0], a1 = As[kk][ty*4+1], a2 = As[kk][ty*4+2], a3 = As[kk][ty*4+3];
      float b0 = Bs[kk][tx*4+0], b1 = Bs[kk][tx*4+1], b2 = Bs[kk][tx*4+2], b3 = Bs[kk][tx*4+3];
      acc[0][0]=fmaf(a0,b0,acc[0][0]); acc[0][1]=fmaf(a0,b1,acc[0][1]); acc[0][2]=fmaf(a0,b2,acc[0][2]); acc[0][3]=fmaf(a0,b3,acc[0][3]);
      acc[1][0]=fmaf(a1,b0,acc[1][0]); acc[1][1]=fmaf(a1,b1,acc[1][1]); acc[1][2]=fmaf(a1,b2,acc[1][2]); acc[1][3]=fmaf(a1,b3,acc[1][3]);
      acc[2][0]=fmaf(a2,b0,acc[2][0]); acc[2][1]=fmaf(a2,b1,acc[2][1]); acc[2][2]=fmaf(a2,b2,acc[2][2]); acc[2][3]=fmaf(a2,b3,acc[2][3]);
      acc[3][0]=fmaf(a3,b0,acc[3][0]); acc[3][1]=fmaf(a3,b1,acc[3][1]); acc[3][2]=fmaf(a3,b2,acc[3][2]); acc[3][3]=fmaf(a3,b3,acc[3][3]);
    }
    __syncthreads();
  }
  #pragma unroll
  for (int i = 0; i < 4; ++i) {
    int row = m0 + ty*4 + i;
    #pragma unroll
    for (int j = 0; j < 4; ++j) {
      int col = n0 + tx*4 + j;
      float v = acc[i][j] + bias[col];
      float xs = 4.f * tanh_fast(v * 0.25f);
      outp[(size_t)row*512 + col]       = 1.f / (1.f + pow_abs(xs * inv_ab, e2b));
      outp[(size_t)row*512 + col + 256] = muS_f(xs, -1.f, 1.f);
    }
  }
}

// ---------- precompute stage 2: QI = lrf@WqI, QG = gf@WqG ----------
__global__ __launch_bounds__(256) void k_pre_q(
    const float* __restrict__ lrf, const float* __restrict__ gf,
    const float* __restrict__ WqI, const float* __restrict__ WqG,
    float* __restrict__ QI, float* __restrict__ QG)
{
  int g_ix = blockIdx.x;
  int half = g_ix >> 4, tile = g_ix & 15;
  int bx = tile & 3, by = tile >> 2;
  int n0 = bx * 64, m0 = by * 64;
  const float* A  = half ? gf  : lrf;
  const float* Bm = half ? WqG : WqI;
  float* outp     = half ? QG  : QI;

  __shared__ float As[16][64];
  __shared__ float Bs[16][64];
  int tid = threadIdx.x, tx = tid & 15, ty = tid >> 4;
  float acc[4][4] = {};
  int am = tid >> 2, ak = (tid & 3) * 4;
  int bk = tid >> 4, bn = (tid & 15) * 4;
  const float* arow = A + (size_t)(m0 + am) * 512;
  for (int k0 = 0; k0 < 512; k0 += 16) {
    float4 av = *(const float4*)(arow + k0 + ak);
    As[ak+0][am] = av.x; As[ak+1][am] = av.y; As[ak+2][am] = av.z; As[ak+3][am] = av.w;
    *(float4*)&Bs[bk][bn] = *(const float4*)(Bm + (size_t)(k0 + bk) * 256 + n0 + bn);
    __syncthreads();
    #pragma unroll
    for (int kk = 0; kk < 16; ++kk) {
      float a0 = As[kk][ty*4+0], a1 = As[kk][ty*4+1], a2 = As[kk][ty*4+2], a3 = As[kk][ty*4+3];
      float b0 = Bs[kk][tx*4+0], b1 = Bs[kk][tx*4+1], b2 = Bs[kk][tx*4+2], b3 = Bs[kk][tx*4+3];
      acc[0][0]=fmaf(a0,b0,acc[0][0]); acc[0][1]=fmaf(a0,b1,acc[0][1]); acc[0][2]=fmaf(a0,b2,acc[0][2]); acc[0][3]=fmaf(a0,b3,acc[0][3]);
      acc[1][0]=fmaf(a1,b0,acc[1][0]); acc[1][1]=fmaf(a1,b1,acc[1][1]); acc[1][2]=fmaf(a1,b2,acc[1][2]); acc[1][3]=fmaf(a1,b3,acc[1][3]);
      acc[2][0]=fmaf(a2,b0,acc[2][0]); acc[2][1]=fmaf(a2,b1,acc[2][1]); acc[2][2]=fmaf(a2,b2,acc[2][2]); acc[2][3]=fmaf(a2,b3,acc[2][3]);
      acc[3][0]=fmaf(a3,b0,acc[3][0]); acc[3][1]=fmaf(a3,b1,acc[3][1]); acc[3][2]=fmaf(a3,b2,acc[3][2]); acc[3][3]=fmaf(a3,b3,acc[3][3]);
    }
    __syncthreads();
  }
  #pragma unroll
  for (int i = 0; i < 4; ++i) {
    float4 v = make_float4(acc[i][0], acc[i][1], acc[i][2], acc[i][3]);
    *(float4*)(outp + (size_t)(m0 + ty*4 + i) * 256 + n0 + tx*4) = v;
  }
}

// ---------- precompute stage 3: qIp = QI@WkIt, qGp = QG@WkGt ----------
__global__ __launch_bounds__(256) void k_pre_qp(
    const float* __restrict__ QI, const float* __restrict__ QG,
    const float* __restrict__ WkIt, const float* __restrict__ WkGt,
    float* __restrict__ qIp, float* __restrict__ qGp)
{
  int g_ix = blockIdx.x;
  int half = g_ix >> 4, tile = g_ix & 15;
  int bx = tile & 3, by = tile >> 2;
  int n0 = bx * 64, m0 = by * 64;
  const float* A  = half ? QG   : QI;
  const float* Bm = half ? WkGt : WkIt;
  float* outp     = half ? qGp  : qIp;

  __shared__ float As[16][64];
  __shared__ float Bs[16][64];
  int tid = threadIdx.x, tx = tid & 15, ty = tid >> 4;
  float acc[4][4] = {};
  int am = tid >> 2, ak = (tid & 3) * 4;
  int bk = tid >> 4, bn = (tid & 15) * 4;
  const float* arow = A + (size_t)(m0 + am) * 256;
  for (int k0 = 0; k0 < 256; k0 += 16) {
    float4 av = *(const float4*)(arow + k0 + ak);
    As[ak+0][am] = av.x; As[ak+1][am] = av.y; As[ak+2][am] = av.z; As[ak+3][am] = av.w;
    *(float4*)&Bs[bk][bn] = *(const float4*)(Bm + (size_t)(k0 + bk) * 256 + n0 + bn);
    __syncthreads();
    #pragma unroll
    for (int kk = 0; kk < 16; ++kk) {
      float a0 = As[kk][ty*4+0], a1 = As[kk][ty*4+1], a2 = As[kk][ty*4+2], a3 = As[kk][ty*4+3];
      float b0 = Bs[kk][tx*4+0], b1 = Bs[kk][tx*4+1], b2 = Bs[kk][tx*4+2], b3 = Bs[kk][tx*4+3];
      acc[0][0]=fmaf(a0,b0,acc[0][0]); acc[0][1]=fmaf(a0,b1,acc[0][1]); acc[0][2]=fmaf(a0,b2,acc[0][2]); acc[0][3]=fmaf(a0,b3,acc[0][3]);
      acc[1][0]=fmaf(a1,b0,acc[1][0]); acc[1][1]=fmaf(a1,b1,acc[1][1]); acc[1][2]=fmaf(a1,b2,acc[1][2]); acc[1][3]=fmaf(a1,b3,acc[1][3]);
      acc[2][0]=fmaf(a2,b0,acc[2][0]); acc[2][1]=fmaf(a2,b1,acc[2][1]); acc[2][2]=fmaf(a2,b2,acc[2][2]); acc[2][3]=fmaf(a2,b3,acc[2][3]);
      acc[3][0]=fmaf(a3,b0,acc[3][0]); acc[3][1]=fmaf(a3,b1,acc[3][1]); acc[3][2]=fmaf(a3,b2,acc[3][2]); acc[3][3]=fmaf(a3,b3,acc[3][3]);
    }
    __syncthreads();
  }
  #pragma unroll
  for (int i = 0; i < 4; ++i) {
    float4 v = make_float4(acc[i][0], acc[i][1], acc[i][2], acc[i][3]);
    *(float4*)(outp + (size_t)(m0 + ty*4 + i) * 256 + n0 + tx*4) = v;
  }
}

// ---------- THE SCAN: one block per batch runs all T=8 steps (batch-diagonal) ----------
__global__ __launch_bounds__(512) void k_scan(
    const unsigned short* __restrict__ FTbf, const float* __restrict__ FTf,
    const float* __restrict__ qIp, const float* __restrict__ qGp,
    const unsigned short* __restrict__ Wv2, const unsigned short* __restrict__ WB,
    const float* __restrict__ b1, const float* __restrict__ bfv,
    const float* __restrict__ biv, const float* __restrict__ b2,
    const unsigned short* __restrict__ B1t, const unsigned short* __restrict__ W2t,
    const float* __restrict__ a_p, const float* __restrict__ b_p,
    unsigned short* __restrict__ Gf, unsigned short* __restrict__ Gi,
    float* __restrict__ out)
{
  __shared__ __align__(16) short Fs[64*264];       // 33792 B, F(st) bf16, persists across steps
  __shared__ __align__(16) short Bstage[64*264];   // 33792 B, B1t chunk
  __shared__ __align__(16) short Wstage[256*72];   // 36864 B, W2t k-chunk
  __shared__ __align__(16) short A2ch[64*72];      //  9216 B, A2 chunk
  __shared__ float qv[512];
  __shared__ float red[512];
  __shared__ float prl[128];
  __shared__ float ftb[512];
  __shared__ float rL[256];
  __shared__ float rWall[1024];

  int b = blockIdx.x, tid = threadIdx.x;
  int w = tid >> 6, lane = tid & 63, lr = lane & 15, lh = lane >> 4;
  int rg = w & 3, cg = w >> 2;                     // wave grid: 4 row-groups x 2 col-groups
  float ab = fmaxf(a_p[0], 0.001f), bb = fmaxf(b_p[0], 0.001f);

  // initial F = FT broadcast; qv constant across steps
  #pragma unroll
  for (int p = 0; p < 4; ++p) {
    int idx = (p*512 + tid) * 8;
    int row = idx >> 8, col = idx & 255;
    *(float4*)&Fs[row*264 + col] = *(const float4*)&FTbf[idx];
  }
  qv[tid] = (tid < 256) ? qIp[(size_t)b*256 + tid] : qGp[(size_t)b*256 + tid - 256];
  __syncthreads();

  const float* Fprev = nullptr;
  for (int st = 0; st < T_; ++st) {
    float* Fout = out + (size_t)(7 - st) * NROW * 256;

    // ---- scores (t<256: I, t>=256: G; 4 partial lanes per k)
    {
      int which = tid >> 8, tt = tid & 255, k = tt & 63, part = tt >> 6;
      const unsigned int* frow = (const unsigned int*)&Fs[k*264 + part*64];
      const float* q0 = qv + which*256 + part*64;
      float s0 = 0.f;
      #pragma unroll
      for (int d2 = 0; d2 < 32; ++d2) {
        unsigned int pr = frow[d2];
        float f0 = __uint_as_float(pr << 16);
        float f1 = __uint_as_float(pr & 0xffff0000u);
        s0 = fmaf(f1, q0[2*d2+1], fmaf(f0, q0[2*d2], s0));
      }
      red[which*256 + tt] = s0;
    }
    __syncthreads();
    if (tid < 128) {
      int which = tid >> 6, kk = tid & 63;
      const float* rp = red + which*256;
      float s = (rp[kk] + rp[64+kk] + rp[128+kk] + rp[192+kk]) * (1.f/16.f);
      float m = s;
      for (int off = 32; off; off >>= 1) m = fmaxf(m, __shfl_xor(m, off, 64));
      float e = fexp2((s - m) * 1.4426950408889634f);
      float sum = e;
      for (int off = 32; off; off >>= 1) sum += __shfl_xor(sum, off, 64);
      prl[which*64 + kk] = e / sum;
    }
    __syncthreads();
    // ---- ftbar
    {
      int which = tid >> 8, tt = tid & 255;
      const float* pp = prl + which*64;
      float f0 = 0.f;
      #pragma unroll 8
      for (int kk = 0; kk < 64; ++kk)
        f0 = fmaf(pp[kk], bfss((unsigned short)Fs[kk*264 + tt]), f0);
      ftb[which*256 + tt] = f0;
    }
    __syncthreads();
    // ---- rt (4 outputs split over halves) + defuzz
    {
      int half = tid >> 8, tt = tid & 255;
      const float* fb = ftb + half*256;
      const unsigned short* wv = Wv2 + half*512 + tt;
      float a0 = 0.f, a1 = 0.f;
      #pragma unroll 4
      for (int d = 0; d < 256; ++d) {
        float fv = fb[d];
        a0 = fmaf(fv, bfss(wv[(size_t)d*1024]),       a0);
        a1 = fmaf(fv, bfss(wv[(size_t)d*1024 + 256]), a1);
      }
      red[half*256 + tt] = defuzz_one(a0, a1, ab, bb);
    }
    __syncthreads();
    if (tid < 256) rL[tid] = 0.5f * (red[tid] + red[256 + tid]);
    __syncthreads();
    // ---- rW (2 outputs/thread) with biases folded in
    {
      float w0 = 0.f, w1 = 0.f;
      const unsigned short* wb0 = WB + tid;
      #pragma unroll 4
      for (int d = 0; d < 256; ++d) {
        float rv = rL[d];
        w0 = fmaf(rv, bfss(wb0[(size_t)d*1024]),       w0);
        w1 = fmaf(rv, bfss(wb0[(size_t)d*1024 + 512]), w1);
      }
      rWall[tid]       = w0 + b1[tid];
      rWall[512 + tid] = w1 + ((tid < 256) ? bfv[tid] : biv[tid - 256]);
    }
    __syncthreads();

    // ---- gate chunks (gemm1 cols 512..1023) -> Gf/Gi global (L2, same CU)
    for (int c = 8; c < 16; ++c) {
      #pragma unroll
      for (int p = 0; p < 4; ++p) {
        int idx = (p*512 + tid) * 8;
        int row = idx >> 8, col = idx & 255;
        *(float4*)&Bstage[row*264 + col] = *(const float4*)&B1t[(size_t)c*16384 + idx];
      }
      __syncthreads();
      #pragma unroll
      for (int f = 0; f < 2; ++f) {
        f32x4 acc = {0.f,0.f,0.f,0.f};
        int nb = cg*32 + f*16;
        #pragma unroll
        for (int ks = 0; ks < 8; ++ks) {
          short8v av = *(const short8v*)&Fs[(rg*16 + lr)*264 + ks*32 + lh*8];
          short8v bv = *(const short8v*)&Bstage[(nb + lr)*264 + ks*32 + lh*8];
          acc = __builtin_amdgcn_mfma_f32_16x16x32_bf16(av, bv, acc, 0, 0, 0);
        }
        int gc = c*64 + nb + lr;       // 512..1023
        float add = rWall[gc];
        int cc = gc - 512;
        #pragma unroll
        for (int r = 0; r < 4; ++r) {
          int row = b*64 + rg*16 + lh*4 + r;
          unsigned short val = f2bf(sigmoid_f(add + tanh_fast(acc[r])));
          if (cc < 256) Gf[(size_t)row*256 + cc]       = val;
          else          Gi[(size_t)row*256 + cc - 256] = val;
        }
      }
      __syncthreads();
    }

    // ---- A2/O chunks (gemm1 cols 0..511 = gemm2 K), O accumulates in registers
    f32x4 O[8];
    #pragma unroll
    for (int nn = 0; nn < 8; ++nn) { O[nn][0]=0.f; O[nn][1]=0.f; O[nn][2]=0.f; O[nn][3]=0.f; }
    for (int c = 0; c < 8; ++c) {
      #pragma unroll
      for (int p = 0; p < 4; ++p) {
        int idx = (p*512 + tid) * 8;
        int row = idx >> 8, col = idx & 255;
        *(float4*)&Bstage[row*264 + col] = *(const float4*)&B1t[(size_t)c*16384 + idx];
      }
      #pragma unroll
      for (int p = 0; p < 4; ++p) {
        int idx = (p*512 + tid) * 8;     // 0..16383 over 256n x 64k
        int n = idx >> 6, kk = idx & 63;
        *(float4*)&Wstage[n*72 + kk] = *(const float4*)&W2t[(size_t)n*512 + c*64 + kk];
      }
      __syncthreads();
      // g1: A2 chunk = gelu(F@B1t_c + rWall)
      #pragma unroll
      for (int f = 0; f < 2; ++f) {
        f32x4 acc = {0.f,0.f,0.f,0.f};
        int nb = cg*32 + f*16;
        #pragma unroll
        for (int ks = 0; ks < 8; ++ks) {
          short8v av = *(const short8v*)&Fs[(rg*16 + lr)*264 + ks*32 + lh*8];
          short8v bv = *(const short8v*)&Bstage[(nb + lr)*264 + ks*32 + lh*8];
          acc = __builtin_amdgcn_mfma_f32_16x16x32_bf16(av, bv, acc, 0, 0, 0);
        }
        int gc = c*64 + nb + lr;         // 0..511
        float add = rWall[gc];
        #pragma unroll
        for (int r = 0; r < 4; ++r)
          A2ch[(rg*16 + lh*4 + r)*72 + nb + lr] = f2bf(gelu_f(acc[r] + add));
      }
      __syncthreads();
      // g2: O += A2chunk @ W2t_c   (O tile per wave: rows rg*16, cols cg*128)
      #pragma unroll
      for (int ks2 = 0; ks2 < 2; ++ks2) {
        short8v av = *(const short8v*)&A2ch[(rg*16 + lr)*72 + ks2*32 + lh*8];
        #pragma unroll
        for (int nn = 0; nn < 8; ++nn) {
          short8v bv = *(const short8v*)&Wstage[(cg*128 + nn*16 + lr)*72 + ks2*32 + lh*8];
          O[nn] = __builtin_amdgcn_mfma_f32_16x16x32_bf16(av, bv, O[nn], 0, 0, 0);
        }
      }
      __syncthreads();
    }

    // ---- epilogue: gates + residual + tanh; write Fout fp32 + update Fs bf16
    #pragma unroll
    for (int nn = 0; nn < 8; ++nn) {
      int col = cg*128 + nn*16 + lr;
      float b2c = b2[col], rv = rL[col];
      #pragma unroll
      for (int r = 0; r < 4; ++r) {
        int rowl = rg*16 + lh*4 + r;
        int row = b*64 + rowl;
        float Ftv = (st == 0) ? FTf[rowl*256 + col] : Fprev[(size_t)row*256 + col];
        float ftld = O[nn][r] + b2c + Ftv + rv;
        float fg = bfss(Gf[(size_t)row*256 + col]);
        float ig = bfss(Gi[(size_t)row*256 + col]);
        float ov = fg * Ftv + ig * tanh_fast(ftld);
        Fout[(size_t)row*256 + col] = ov;
        Fs[rowl*264 + col] = f2bf(ov);
      }
    }
    Fprev = Fout;
    __syncthreads();
  }
}

// ---------- host ----------
extern "C" void kernel_launch(void* const* d_in, const int* in_sizes, int n_in,
                              void* d_out, int out_size, void* d_ws, size_t ws_size,
                              hipStream_t stream)
{
  (void)in_sizes; (void)n_in; (void)out_size; (void)ws_size;
  const float* wsi  = (const float*)d_in[0];
  const float* gen  = (const float*)d_in[1];
  const float* FT   = (const float*)d_in[2];
  const float* W_lr = (const float*)d_in[3];
  const float* b_lr = (const float*)d_in[4];
  const float* W_g  = (const float*)d_in[5];
  const float* b_g  = (const float*)d_in[6];
  const float* WqI  = (const float*)d_in[7];
  const float* WqG  = (const float*)d_in[8];
  const float* WkI  = (const float*)d_in[9];
  const float* WkG  = (const float*)d_in[10];
  const float* WvI  = (const float*)d_in[11];
  const float* WvG  = (const float*)d_in[12];
  const float* W1   = (const float*)d_in[13];
  const float* b1   = (const float*)d_in[14];
  const float* W2   = (const float*)d_in[15];
  const float* b2   = (const float*)d_in[16];
  const float* Wf   = (const float*)d_in[17];
  const float* bf   = (const float*)d_in[18];
  const float* Wi   = (const float*)d_in[19];
  const float* bi   = (const float*)d_in[20];
  const float* Vf   = (const float*)d_in[21];
  const float* Vi   = (const float*)d_in[22];
  const float* a_p  = (const float*)d_in[23];
  const float* b_p  = (const float*)d_in[24];

  float* out = (float*)d_out;
  float* ws  = (float*)d_ws;
  // fp32 region
  float* qIp   = ws;                    // 256*256
  float* qGp   = qIp   + 65536;
  float* lrf   = qGp   + 65536;         // 256*512
  float* gf    = lrf   + 131072;
  float* QI    = gf    + 131072;
  float* QG    = QI    + 65536;
  float* WkIt  = QG    + 65536;
  float* WkGt  = WkIt  + 65536;
  // bf16 region
  unsigned short* Gfb  = (unsigned short*)(WkGt + 65536);  // 16384*256
  unsigned short* Gib  = Gfb  + 4194304;                   // 16384*256
  unsigned short* FTbf = Gib  + 4194304;                   // 64*256
  unsigned short* B1t  = FTbf + 16384;                     // 1024*256
  unsigned short* W2t  = B1t  + 262144;                    // 256*512
  unsigned short* Wv2  = W2t  + 131072;                    // 256*1024
  unsigned short* WB   = Wv2  + 262144;                    // 256*1024

  k_convert<<<4160, 256, 0, stream>>>(W1, Vf, Vi, W2, FT, WkI, WkG, WvI, WvG, Wf, Wi,
                                      B1t, W2t, FTbf, WkIt, WkGt, Wv2, WB);
  k_pre_lin<<<32, 256, 0, stream>>>(wsi, gen, W_lr, b_lr, W_g, b_g, a_p, b_p, lrf, gf);
  k_pre_q<<<32, 256, 0, stream>>>(lrf, gf, WqI, WqG, QI, QG);
  k_pre_qp<<<32, 256, 0, stream>>>(QI, QG, WkIt, WkGt, qIp, qGp);

  k_scan<<<256, 512, 0, stream>>>(FTbf, FT, qIp, qGp, Wv2, WB,
                                  b1, bf, bi, b2, B1t, W2t, a_p, b_p,
                                  Gfb, Gib, out);
}